// Round 10
// baseline (267.316 us; speedup 1.0000x reference)
//
#include <hip/hip_runtime.h>
#include <math.h>

// dims
constexpr int Nn = 1024, Bb = 8, HIDc = 256, Hh = 8, DHc = 32;
constexpr int TSTR = 520;   // trans row stride (bf16 elems); 1040 B = odd multiple of 16 B

typedef __bf16 bf16x8 __attribute__((ext_vector_type(8)));
typedef __bf16 bf16x4 __attribute__((ext_vector_type(4)));
typedef float  f32x4  __attribute__((ext_vector_type(4)));

// ---------------------------------------------------------------------------
// prep_k: fused one-time preprocessing (unchanged from round 9).
// ---------------------------------------------------------------------------
struct WCvtArgs {
    const float* src[9];
    int K[9], M[9], dstOff[9], tiles[9];
};

__global__ __launch_bounds__(256)
void prep_k(WCvtArgs a, __bf16* __restrict__ Wt,
            const int* __restrict__ dist, unsigned char* __restrict__ mp,
            const float* __restrict__ nodes, __bf16* __restrict__ xinb)
{
    __shared__ float ts[32][33];
    const int tid = threadIdx.x;
    if (blockIdx.x < 1088) {
        int bid = blockIdx.x, i = 0;
        while (bid >= a.tiles[i]) { bid -= a.tiles[i]; ++i; }
        const int K = a.K[i], M = a.M[i];
        const int tilesM = M >> 5;
        const int m0 = (bid % tilesM) << 5, k0 = (bid / tilesM) << 5;
        const float* src = a.src[i];
        __bf16* dst = Wt + a.dstOff[i];
        const int tx = tid & 31, ty = tid >> 5;
        #pragma unroll
        for (int j = 0; j < 4; ++j)
            ts[ty + 8 * j][tx] = src[(size_t)(k0 + ty + 8 * j) * M + m0 + tx];
        __syncthreads();
        #pragma unroll
        for (int j = 0; j < 4; ++j)
            dst[(size_t)(m0 + ty + 8 * j) * K + k0 + tx] = (__bf16)ts[tx][ty + 8 * j];
    } else if (blockIdx.x < 3136) {
        const int idx = (blockIdx.x - 1088) * 256 + tid;   // 524288 items
        const int quad = idx & 3, c = (idx >> 2) & 15, q = (idx >> 6) & 1023, b = idx >> 16;
        const int* dp = dist + ((((size_t)b << 10) + q) << 10) + c * 64 + quad * 4;
        uchar4 out;
        unsigned char* po = &out.x;
        #pragma unroll
        for (int t = 0; t < 4; ++t) {
            const int4 v = *(const int4*)(dp + t * 16);
            unsigned int code = 0;
            const int dd[4] = {v.x, v.y, v.z, v.w};
            #pragma unroll
            for (int r = 0; r < 4; ++r)
                code |= ((dd[r] == 1 ? 1u : 0u) | (dd[r] >= 1 ? 2u : 0u)) << (2 * r);
            po[t] = (unsigned char)code;
        }
        *(uchar4*)(mp + ((((size_t)b << 10) + q) << 8) + (c << 4) + (quad << 2)) = out;
    } else {
        const int idx = (blockIdx.x - 3136) * 256 + tid;   // 1M items
        const int token = idx >> 7, k2 = (idx & 127) * 2;  // token = b*1024 + n
        const int b = token >> 10, n = token & 1023;
        const float e = (float)k2 * (1.0f / 256.0f);
        const float freq = exp2f(-13.287712379549449f * e);
        const float ang = (float)n * freq;
        const float2 nd = *(const float2*)(nodes + ((size_t)(n * 8 + b)) * 256 + k2);
        __bf16* p = xinb + (size_t)token * 256 + k2;
        p[0] = (__bf16)(nd.x + sinf(ang));
        p[1] = (__bf16)(nd.y + cosf(ang));
    }
}

// ---------------------------------------------------------------------------
// gemmT: D^T = W * X^T. A = weight rows (DIRECT from global, per-wave strip,
// rolling 4-chunk register prefetch => 8+ loads in flight/lane). B = token
// activations from LDS (ds_read_b128). ZERO barriers inside.
// Wave owns 64 output channels (4 m-tiles) x NJ*16 tokens.
// ---------------------------------------------------------------------------
template<int KK, int NJ>
__device__ __forceinline__ void gemmT(const __bf16* __restrict__ wrow,
                                      const __bf16* __restrict__ x0,
                                      const __bf16* __restrict__ x1,
                                      f32x4 acc[4][2])
{
    constexpr int NKC = KK / 32;
    bf16x8 wA[4][4];
    #pragma unroll
    for (int p = 0; p < 4; ++p)
        #pragma unroll
        for (int t = 0; t < 4; ++t)
            wA[p][t] = *(const bf16x8*)(wrow + (size_t)(t * 16) * KK + p * 32);
    #pragma unroll
    for (int t = 0; t < 4; ++t) {
        acc[t][0] = (f32x4){0.f, 0.f, 0.f, 0.f};
        if (NJ == 2) acc[t][1] = (f32x4){0.f, 0.f, 0.f, 0.f};
    }
    #pragma unroll
    for (int kc = 0; kc < NKC; ++kc) {
        const bf16x8 b0 = *(const bf16x8*)(x0 + kc * 32);
        bf16x8 b1;
        if (NJ == 2) b1 = *(const bf16x8*)(x1 + kc * 32);
        const int cur = kc & 3;
        #pragma unroll
        for (int t = 0; t < 4; ++t) {
            acc[t][0] = __builtin_amdgcn_mfma_f32_16x16x32_bf16(wA[cur][t], b0, acc[t][0], 0, 0, 0);
            if (NJ == 2)
                acc[t][1] = __builtin_amdgcn_mfma_f32_16x16x32_bf16(wA[cur][t], b1, acc[t][1], 0, 0, 0);
        }
        if (kc + 4 < NKC)
            #pragma unroll
            for (int t = 0; t < 4; ++t)
                wA[cur][t] = *(const bf16x8*)(wrow + (size_t)(t * 16) * KK + (kc + 4) * 32);
    }
}

// ---------------------------------------------------------------------------
// layer_k: fused transformer block slab, D^T formulation.
// Block = NJ*16 tokens (NJ=2: 32 tokens, 256 blocks), 4 waves = 4 m-strips.
// Lane holds (token = j*16+col) x (m = cq*64 + t*16 + quad*4 + r).
//   stage A: y = Ain @ w0 + b0 (+xres) -> LN(g1,be1) -> trans
//   FFN: h1 = relu(. @ w1 + b1) (512 wide) -> trans; y2 = h1 @ w2 + b2 + LN1 -> LN2
//   QKV: q(scaled)/k -> (B,H,N,DH) b64 stores; v -> V^T scatter
//   BNOUT (NJ=1, 1 block): batch-norm over b at n=0 -> d_out
// ~8 barriers total (vs ~52 in the staged-weight version).
// ---------------------------------------------------------------------------
template<bool RESID, bool FFN, bool QKV, bool N0ROWS, bool XGATE, bool BNOUT, int NJ>
__global__ __launch_bounds__(256)
void layer_k(const __bf16* __restrict__ Ain, const float* __restrict__ xres,
             const __bf16* __restrict__ w0, const float* __restrict__ b0,
             const float* __restrict__ g1, const float* __restrict__ be1,
             const __bf16* __restrict__ w1, const float* __restrict__ b1_,
             const __bf16* __restrict__ w2, const float* __restrict__ b2_,
             const float* __restrict__ g2, const float* __restrict__ be2,
             const __bf16* __restrict__ wq, const float* __restrict__ bq, int qfull,
             const float* __restrict__ bng, const float* __restrict__ bnb,
             float* __restrict__ xout,
             __bf16* __restrict__ qb, __bf16* __restrict__ kb, __bf16* __restrict__ vtb)
{
    __shared__ __bf16 trans[32][TSTR];
    __shared__ float red[4][32][2];

    const int tid = threadIdx.x;
    const int lane = tid & 63;
    const int cq = tid >> 6;                 // wave = m-strip
    const int col = lane & 15, quad = lane >> 4;
    const int row0 = blockIdx.x * (NJ * 16);
    const int mb = cq * 64;

    // ---- stage Ain -> trans ----
    #pragma unroll
    for (int i = 0; i < 2; ++i) {
        const int v = i * 256 + tid;
        const int rw = v >> 4, cc = (v & 15) * 16;
        const int rg = N0ROWS ? ((rw & 7) << 10) : (row0 + rw);
        *(bf16x8*)&trans[rw][cc]     = *(const bf16x8*)(Ain + (size_t)rg * 256 + cc);
        *(bf16x8*)&trans[rw][cc + 8] = *(const bf16x8*)(Ain + (size_t)rg * 256 + cc + 8);
    }
    __syncthreads();

    const __bf16* x0 = &trans[col][quad * 8];
    const __bf16* x1 = &trans[16 + col][quad * 8];
    int tg[2];
    #pragma unroll
    for (int j = 0; j < NJ; ++j)
        tg[j] = N0ROWS ? ((j * 16 + col) & 7) << 10 : (row0 + j * 16 + col);

    // ---- stage A ----
    f32x4 acc[4][2];
    gemmT<256, NJ>(w0 + (size_t)(mb + col) * 256 + quad * 8, x0, x1, acc);

    float val[2][4][4];   // [j][t][r] — LN1 outputs, reused as LN2 residual
    {
        float4 bb4[4], gm4[4], bt4[4];
        #pragma unroll
        for (int t = 0; t < 4; ++t) {
            const int cb = mb + t * 16 + quad * 4;
            bb4[t] = *(const float4*)&b0[cb];
            gm4[t] = *(const float4*)&g1[cb];
            bt4[t] = *(const float4*)&be1[cb];
        }
        #pragma unroll
        for (int j = 0; j < NJ; ++j) {
            float s1 = 0.f, s2 = 0.f;
            #pragma unroll
            for (int t = 0; t < 4; ++t) {
                float4 xr4 = {0.f, 0.f, 0.f, 0.f};
                if (RESID) xr4 = *(const float4*)&xres[(size_t)tg[j] * 256 + mb + t * 16 + quad * 4];
                const float* bbp = (const float*)&bb4[t];
                const float* xrp = (const float*)&xr4;
                #pragma unroll
                for (int r = 0; r < 4; ++r) {
                    float v = acc[t][j][r] + bbp[r] + xrp[r];
                    val[j][t][r] = v; s1 += v; s2 += v * v;
                }
            }
            s1 += __shfl_xor(s1, 16); s1 += __shfl_xor(s1, 32);
            s2 += __shfl_xor(s2, 16); s2 += __shfl_xor(s2, 32);
            if (quad == 0) { red[cq][j * 16 + col][0] = s1; red[cq][j * 16 + col][1] = s2; }
        }
        __syncthreads();
        #pragma unroll
        for (int j = 0; j < NJ; ++j) {
            const int tk = j * 16 + col;
            const float s1 = red[0][tk][0] + red[1][tk][0] + red[2][tk][0] + red[3][tk][0];
            const float s2 = red[0][tk][1] + red[1][tk][1] + red[2][tk][1] + red[3][tk][1];
            const float mu = s1 * (1.0f / 256.0f);
            const float rv = rsqrtf(s2 * (1.0f / 256.0f) - mu * mu + 1e-5f);
            #pragma unroll
            for (int t = 0; t < 4; ++t) {
                const float* gmp = (const float*)&gm4[t];
                const float* btp = (const float*)&bt4[t];
                bf16x4 o4; float4 of;
                #pragma unroll
                for (int r = 0; r < 4; ++r) {
                    const float o = (val[j][t][r] - mu) * rv * gmp[r] + btp[r];
                    val[j][t][r] = o;
                    o4[r] = (__bf16)o;
                    ((float*)&of)[r] = o;
                }
                *(bf16x4*)&trans[tk][mb + t * 16 + quad * 4] = o4;
                if (!FFN)   // fused1: full x write
                    *(float4*)&xout[(size_t)tg[j] * 256 + mb + t * 16 + quad * 4] = of;
            }
        }
        __syncthreads();
    }

    if (FFN) {
        // ---- h1 = relu(LN1 @ W1 + b1), M=512 in two m-passes ----
        bf16x4 h1p[2][2][4];   // [mh][j][t]
        #pragma unroll
        for (int mh = 0; mh < 2; ++mh) {
            f32x4 a1[4][2];
            gemmT<256, NJ>(w1 + (size_t)(mh * 256 + mb + col) * 256 + quad * 8, x0, x1, a1);
            #pragma unroll
            for (int t = 0; t < 4; ++t) {
                const float4 bh4 = *(const float4*)&b1_[mh * 256 + mb + t * 16 + quad * 4];
                const float* bhp = (const float*)&bh4;
                #pragma unroll
                for (int j = 0; j < NJ; ++j)
                    #pragma unroll
                    for (int r = 0; r < 4; ++r)
                        h1p[mh][j][t][r] = (__bf16)fmaxf(a1[t][j][r] + bhp[r], 0.f);
            }
        }
        __syncthreads();
        #pragma unroll
        for (int mh = 0; mh < 2; ++mh)
            #pragma unroll
            for (int j = 0; j < NJ; ++j)
                #pragma unroll
                for (int t = 0; t < 4; ++t)
                    *(bf16x4*)&trans[j * 16 + col][mh * 256 + mb + t * 16 + quad * 4] = h1p[mh][j][t];
        __syncthreads();

        // ---- y2 = h1 @ W2 + b2 + LN1 -> LN2 ----
        f32x4 a2[4][2];
        gemmT<512, NJ>(w2 + (size_t)(mb + col) * 512 + quad * 8, x0, x1, a2);

        float4 bb4[4], gm4[4], bt4[4];
        #pragma unroll
        for (int t = 0; t < 4; ++t) {
            const int cb = mb + t * 16 + quad * 4;
            bb4[t] = *(const float4*)&b2_[cb];
            gm4[t] = *(const float4*)&g2[cb];
            bt4[t] = *(const float4*)&be2[cb];
        }
        #pragma unroll
        for (int j = 0; j < NJ; ++j) {
            float s1 = 0.f, s2 = 0.f;
            #pragma unroll
            for (int t = 0; t < 4; ++t) {
                const float* bbp = (const float*)&bb4[t];
                #pragma unroll
                for (int r = 0; r < 4; ++r) {
                    const float v = a2[t][j][r] + bbp[r] + val[j][t][r];
                    val[j][t][r] = v; s1 += v; s2 += v * v;
                }
            }
            s1 += __shfl_xor(s1, 16); s1 += __shfl_xor(s1, 32);
            s2 += __shfl_xor(s2, 16); s2 += __shfl_xor(s2, 32);
            if (quad == 0) { red[cq][j * 16 + col][0] = s1; red[cq][j * 16 + col][1] = s2; }
        }
        __syncthreads();
        #pragma unroll
        for (int j = 0; j < NJ; ++j) {
            const int tk = j * 16 + col;
            const float s1 = red[0][tk][0] + red[1][tk][0] + red[2][tk][0] + red[3][tk][0];
            const float s2 = red[0][tk][1] + red[1][tk][1] + red[2][tk][1] + red[3][tk][1];
            const float mu = s1 * (1.0f / 256.0f);
            const float rv = rsqrtf(s2 * (1.0f / 256.0f) - mu * mu + 1e-5f);
            #pragma unroll
            for (int t = 0; t < 4; ++t) {
                const float* gmp = (const float*)&gm4[t];
                const float* btp = (const float*)&bt4[t];
                bf16x4 o4; float4 of;
                #pragma unroll
                for (int r = 0; r < 4; ++r) {
                    const float o = (val[j][t][r] - mu) * rv * gmp[r] + btp[r];
                    val[j][t][r] = o;
                    o4[r] = (__bf16)o;
                    ((float*)&of)[r] = o;
                }
                if (QKV) *(bf16x4*)&trans[tk][mb + t * 16 + quad * 4] = o4;
                if (!BNOUT) {
                    const bool wr = XGATE ? ((tg[j] & 1023) == 0) : true;
                    if (wr) *(float4*)&xout[(size_t)tg[j] * 256 + mb + t * 16 + quad * 4] = of;
                }
            }
        }
        if (BNOUT) {
            // batch-norm over b: tokens are cols (col&7 = b, duplicated x2)
            #pragma unroll
            for (int t = 0; t < 4; ++t) {
                const int cb = mb + t * 16 + quad * 4;
                const float4 g4 = *(const float4*)&bng[cb];
                const float4 bB = *(const float4*)&bnb[cb];
                float4 of;
                #pragma unroll
                for (int r = 0; r < 4; ++r) {
                    float s1 = val[0][t][r], s2 = val[0][t][r] * val[0][t][r];
                    s1 += __shfl_xor(s1, 1); s2 += __shfl_xor(s2, 1);
                    s1 += __shfl_xor(s1, 2); s2 += __shfl_xor(s2, 2);
                    s1 += __shfl_xor(s1, 4); s2 += __shfl_xor(s2, 4);
                    s1 += __shfl_xor(s1, 8); s2 += __shfl_xor(s2, 8);
                    const float mu = s1 * (1.0f / 16.0f);     // 2x duplicated 8-sum
                    const float rv = rsqrtf(s2 * (1.0f / 16.0f) - mu * mu + 1e-5f);
                    ((float*)&of)[r] = (val[0][t][r] - mu) * rv * ((const float*)&g4)[r]
                                       + ((const float*)&bB)[r];
                }
                if (col < 8)
                    *(float4*)&xout[(size_t)col * 256 + cb] = of;
            }
        }
        __syncthreads();
    }

    if (QKV) {
        const int b_ = N0ROWS ? 0 : (row0 >> 10);
        const bool qneed = qfull || ((row0 & 1023) < 128);
        for (int cg = 0; cg < 3; ++cg) {
            if (cg == 0 && !qneed) continue;   // block-uniform skip
            f32x4 aq[4][2];
            gemmT<256, NJ>(wq + (size_t)(cg * 256 + mb + col) * 256 + quad * 8, x0, x1, aq);
            const float qs = (cg == 0) ? 0.25505402616305625f : 1.0f;  // log2e/sqrt(32)
            #pragma unroll
            for (int t = 0; t < 4; ++t) {
                const int cc = mb + t * 16;
                const int h = cc >> 5;
                const int dhb = (cc & 31) + quad * 4;
                const float4 bq4 = *(const float4*)&bq[cg * 256 + cc + quad * 4];
                const float* bqp = (const float*)&bq4;
                #pragma unroll
                for (int j = 0; j < NJ; ++j) {
                    const int n = tg[j] & 1023;
                    if (cg == 2) {
                        #pragma unroll
                        for (int r = 0; r < 4; ++r)
                            vtb[((size_t)(b_ * 8 + h) * 32 + dhb + r) * 1024 + n] =
                                (__bf16)(aq[t][j][r] + bqp[r]);
                    } else {
                        bf16x4 p;
                        #pragma unroll
                        for (int r = 0; r < 4; ++r)
                            p[r] = (__bf16)((aq[t][j][r] + bqp[r]) * qs);
                        __bf16* dst = (cg == 0) ? qb : kb;
                        *(bf16x4*)&dst[((size_t)(b_ * 8 + h) * 1024 + n) * 32 + dhb] = p;
                    }
                }
            }
        }
    }
}

// ---------------------------------------------------------------------------
// MFMA flash attention (unchanged). Grid (64 bh-swizzled, q-chunks).
// ---------------------------------------------------------------------------
__global__ __launch_bounds__(256)
void attn_mfma(const __bf16* __restrict__ Qb, const __bf16* __restrict__ Kb,
               const __bf16* __restrict__ Vt, const unsigned char* __restrict__ MP,
               __bf16* __restrict__ O)
{
    __shared__ __bf16 pbuf[2][4][2][16][72];
    const int tid = threadIdx.x;
    const int lane = tid & 63;
    const int wv = tid >> 6;
    const int col = lane & 15;
    const int quad = lane >> 4;
    const int xr = blockIdx.x;
    const int bh = ((xr & 7) << 3) | (xr >> 3);     // XCD = x%8 = batch b
    const int b = bh >> 3, h = bh & 7;
    const int qbase = blockIdx.y * 128 + wv * 32;
    const int hsel = (h < 2) ? 0 : 1;
    const bool masked = (h < 6);

    bf16x8 qf[2];
    #pragma unroll
    for (int j = 0; j < 2; ++j)
        qf[j] = *(const bf16x8*)(Qb + ((size_t)bh * Nn + qbase + j * 16 + col) * DHc + quad * 8);

    bf16x8 onesf;
    {
        const __bf16 one = (__bf16)1.0f, zero = (__bf16)0.0f;
        #pragma unroll
        for (int j = 0; j < 8; ++j) onesf[j] = (col == 0) ? one : zero;
    }

    f32x4 O0[2], O1[2], OL[2];
    #pragma unroll
    for (int j = 0; j < 2; ++j) {
        O0[j] = (f32x4){0.f, 0.f, 0.f, 0.f};
        O1[j] = (f32x4){0.f, 0.f, 0.f, 0.f};
        OL[j] = (f32x4){0.f, 0.f, 0.f, 0.f};
    }
    const f32x4 zf = {0.f, 0.f, 0.f, 0.f};
    const __bf16* kbase = Kb + (size_t)bh * Nn * DHc;

    bf16x8 kf[4];
    #pragma unroll
    for (int t = 0; t < 4; ++t)
        kf[t] = *(const bf16x8*)(kbase + (size_t)(t * 16 + col) * DHc + quad * 8);

    for (int c = 0; c < 16; ++c) {
        bf16x8 kn[4];
        if (c < 15)
            #pragma unroll
            for (int t = 0; t < 4; ++t)
                kn[t] = *(const bf16x8*)(kbase + (size_t)((c + 1) * 64 + t * 16 + col) * DHc + quad * 8);
        uchar4 mk[2];
        if (masked)
            #pragma unroll
            for (int j = 0; j < 2; ++j)
                mk[j] = *(const uchar4*)(MP + ((((size_t)b << 10) + qbase + j * 16 + col) << 8)
                                            + (c << 4) + (quad << 2));
        #pragma unroll
        for (int j = 0; j < 2; ++j) {
            f32x4 S[4];
            #pragma unroll
            for (int t = 0; t < 4; ++t)
                S[t] = __builtin_amdgcn_mfma_f32_16x16x32_bf16(kf[t], qf[j], zf, 0, 0, 0);
            if (masked) {
                const unsigned char mb2[4] = {mk[j].x, mk[j].y, mk[j].z, mk[j].w};
                #pragma unroll
                for (int t = 0; t < 4; ++t)
                    #pragma unroll
                    for (int r = 0; r < 4; ++r)
                        if (!((mb2[t] >> (2 * r + hsel)) & 1)) S[t][r] = -INFINITY;
            }
            #pragma unroll
            for (int t = 0; t < 4; ++t) {
                bf16x4 p4;
                #pragma unroll
                for (int r = 0; r < 4; ++r)
                    p4[r] = (__bf16)__builtin_amdgcn_exp2f(S[t][r]);
                *(bf16x4*)(&pbuf[c & 1][wv][j][col][t * 16 + quad * 4]) = p4;
            }
        }
        const __bf16* vp = Vt + (size_t)bh * DHc * Nn + c * 64 + quad * 8;
        #pragma unroll
        for (int kh = 0; kh < 2; ++kh) {
            const bf16x8 v0 = *(const bf16x8*)(vp + (size_t)col * Nn + kh * 32);
            const bf16x8 v1 = *(const bf16x8*)(vp + (size_t)(col + 16) * Nn + kh * 32);
            #pragma unroll
            for (int j = 0; j < 2; ++j) {
                const bf16x8 pf = *(const bf16x8*)(&pbuf[c & 1][wv][j][col][kh * 32 + quad * 8]);
                O0[j] = __builtin_amdgcn_mfma_f32_16x16x32_bf16(pf, v0, O0[j], 0, 0, 0);
                O1[j] = __builtin_amdgcn_mfma_f32_16x16x32_bf16(pf, v1, O1[j], 0, 0, 0);
                OL[j] = __builtin_amdgcn_mfma_f32_16x16x32_bf16(pf, onesf, OL[j], 0, 0, 0);
            }
        }
        if (c < 15)
            #pragma unroll
            for (int t = 0; t < 4; ++t) kf[t] = kn[t];
    }
    #pragma unroll
    for (int j = 0; j < 2; ++j)
        #pragma unroll
        for (int r = 0; r < 4; ++r) {
            const float Lr = __shfl(OL[j][r], lane & 48);
            const float inv = 1.0f / Lr;
            const int q = qbase + j * 16 + quad * 4 + r;
            __bf16* op = O + ((size_t)(b * 1024 + q)) * 256 + h * 32 + col;
            op[0]  = (__bf16)(O0[j][r] * inv);
            op[16] = (__bf16)(O1[j][r] * inv);
        }
}

extern "C" void kernel_launch(void* const* d_in, const int* in_sizes, int n_in,
                              void* d_out, int out_size, void* d_ws, size_t ws_size,
                              hipStream_t stream)
{
    const float* nodes   = (const float*)d_in[0];
    const int*   dist    = (const int*)  d_in[1];
    const float* W_in    = (const float*)d_in[2];
    const float* b_in    = (const float*)d_in[3];
    const float* ln_in_g = (const float*)d_in[4];
    const float* ln_in_b = (const float*)d_in[5];
    const float* Wqkv    = (const float*)d_in[6];
    const float* bqkv    = (const float*)d_in[7];
    const float* Wo      = (const float*)d_in[8];
    const float* bo      = (const float*)d_in[9];
    const float* ln1_g   = (const float*)d_in[10];
    const float* ln1_b   = (const float*)d_in[11];
    const float* W1      = (const float*)d_in[12];
    const float* b1      = (const float*)d_in[13];
    const float* W2      = (const float*)d_in[14];
    const float* b2      = (const float*)d_in[15];
    const float* ln2_g   = (const float*)d_in[16];
    const float* ln2_b   = (const float*)d_in[17];
    const float* bn_g    = (const float*)d_in[18];
    const float* bn_b    = (const float*)d_in[19];

    // workspace (byte offsets), 28.25 MB used
    char* ws = (char*)d_ws;
    float*  x   = (float*)(ws);                          // 8 MB fp32 residual (B,N,HID)
    unsigned char* mp = (unsigned char*)(ws + 8388608);  // 2 MB packed mask
    __bf16* wt  = (__bf16*)(ws + 10485760);              // 2.25 MB weights^T
    __bf16* qb  = (__bf16*)(ws + 12845056);              // 4 MB
    __bf16* kb  = (__bf16*)(ws + 17039360);              // 4 MB
    __bf16* vtb = (__bf16*)(ws + 21233664);              // 4 MB (V^T)
    __bf16* ob  = (__bf16*)(ws + 25427968);              // 4 MB attn out
    __bf16* xinb = ob;   // aliases ob (ob first written after fused1 consumed xinb)

    WCvtArgs wa;
    wa.src[0] = W_in;           wa.K[0] = 256; wa.M[0] = 256; wa.dstOff[0] = 0;
    wa.src[1] = Wqkv;           wa.K[1] = 256; wa.M[1] = 768; wa.dstOff[1] = 65536;
    wa.src[2] = Wqkv + 196608;  wa.K[2] = 256; wa.M[2] = 768; wa.dstOff[2] = 262144;
    wa.src[3] = Wo;             wa.K[3] = 256; wa.M[3] = 256; wa.dstOff[3] = 458752;
    wa.src[4] = Wo + 65536;     wa.K[4] = 256; wa.M[4] = 256; wa.dstOff[4] = 524288;
    wa.src[5] = W1;             wa.K[5] = 256; wa.M[5] = 512; wa.dstOff[5] = 589824;
    wa.src[6] = W1 + 131072;    wa.K[6] = 256; wa.M[6] = 512; wa.dstOff[6] = 720896;
    wa.src[7] = W2;             wa.K[7] = 512; wa.M[7] = 256; wa.dstOff[7] = 851968;
    wa.src[8] = W2 + 131072;    wa.K[8] = 512; wa.M[8] = 256; wa.dstOff[8] = 983040;
    for (int i = 0; i < 9; ++i) wa.tiles[i] = (wa.K[i] >> 5) * (wa.M[i] >> 5);

    prep_k<<<7232, 256, 0, stream>>>(wa, wt, dist, mp, nodes, xinb);

    // fused1: x = LN(xin @ W_in + b_in); QKV layer 0 (full q)
    layer_k<false, false, true, false, false, false, 2><<<256, 256, 0, stream>>>(
        xinb, nullptr, wt, b_in, ln_in_g, ln_in_b,
        nullptr, nullptr, nullptr, nullptr, nullptr, nullptr,
        wt + 65536, bqkv, 1, nullptr, nullptr, x, qb, kb, vtb);

    attn_mfma<<<dim3(64, 8), 256, 0, stream>>>(qb, kb, vtb, mp, ob);

    // fused2: Wo0+LN1+FFN0+LN2 (x stored only n==0); QKV layer 1 (q only n<128)
    layer_k<true, true, true, false, true, false, 2><<<256, 256, 0, stream>>>(
        ob, x, wt + 458752, bo, ln1_g, ln1_b,
        wt + 589824, b1, wt + 851968, b2, ln2_g, ln2_b,
        wt + 262144, bqkv + 768, 0, nullptr, nullptr, x, qb, kb, vtb);

    // attn layer 1: only q in [0,128) needed (output consumed only at n==0)
    attn_mfma<<<dim3(64, 1), 256, 0, stream>>>(qb, kb, vtb, mp, ob);

    // fused3: Wo1+LN1+FFN1+LN2 + batch-norm on the 8 n==0 rows (1 block)
    layer_k<true, true, false, true, true, true, 1><<<1, 256, 0, stream>>>(
        ob, x, wt + 524288, bo + 256, ln1_g + 256, ln1_b + 256,
        wt + 720896, b1 + 512, wt + 983040, b2 + 256, ln2_g + 256, ln2_b + 256,
        nullptr, nullptr, 0, bn_g, bn_b, (float*)d_out, nullptr, nullptr, nullptr);
}

// Round 11
// 258.740 us; speedup vs baseline: 1.0331x; 1.0331x over previous
//
#include <hip/hip_runtime.h>
#include <math.h>

// dims
constexpr int Nn = 1024, Bb = 8, HIDc = 256, Hh = 8, DHc = 32;
constexpr int TSTR = 520;   // trans row stride (bf16 elems)

typedef __bf16 bf16x8 __attribute__((ext_vector_type(8)));
typedef __bf16 bf16x4 __attribute__((ext_vector_type(4)));
typedef float  f32x4  __attribute__((ext_vector_type(4)));

// ---------------------------------------------------------------------------
// prep_k: fused one-time preprocessing (unchanged).
// ---------------------------------------------------------------------------
struct WCvtArgs {
    const float* src[9];
    int K[9], M[9], dstOff[9], tiles[9];
};

__global__ __launch_bounds__(256)
void prep_k(WCvtArgs a, __bf16* __restrict__ Wt,
            const int* __restrict__ dist, unsigned char* __restrict__ mp,
            const float* __restrict__ nodes, __bf16* __restrict__ xinb)
{
    __shared__ float ts[32][33];
    const int tid = threadIdx.x;
    if (blockIdx.x < 1088) {
        int bid = blockIdx.x, i = 0;
        while (bid >= a.tiles[i]) { bid -= a.tiles[i]; ++i; }
        const int K = a.K[i], M = a.M[i];
        const int tilesM = M >> 5;
        const int m0 = (bid % tilesM) << 5, k0 = (bid / tilesM) << 5;
        const float* src = a.src[i];
        __bf16* dst = Wt + a.dstOff[i];
        const int tx = tid & 31, ty = tid >> 5;
        #pragma unroll
        for (int j = 0; j < 4; ++j)
            ts[ty + 8 * j][tx] = src[(size_t)(k0 + ty + 8 * j) * M + m0 + tx];
        __syncthreads();
        #pragma unroll
        for (int j = 0; j < 4; ++j)
            dst[(size_t)(m0 + ty + 8 * j) * K + k0 + tx] = (__bf16)ts[tx][ty + 8 * j];
    } else if (blockIdx.x < 3136) {
        const int idx = (blockIdx.x - 1088) * 256 + tid;   // 524288 items
        const int quad = idx & 3, c = (idx >> 2) & 15, q = (idx >> 6) & 1023, b = idx >> 16;
        const int* dp = dist + ((((size_t)b << 10) + q) << 10) + c * 64 + quad * 4;
        uchar4 out;
        unsigned char* po = &out.x;
        #pragma unroll
        for (int t = 0; t < 4; ++t) {
            const int4 v = *(const int4*)(dp + t * 16);
            unsigned int code = 0;
            const int dd[4] = {v.x, v.y, v.z, v.w};
            #pragma unroll
            for (int r = 0; r < 4; ++r)
                code |= ((dd[r] == 1 ? 1u : 0u) | (dd[r] >= 1 ? 2u : 0u)) << (2 * r);
            po[t] = (unsigned char)code;
        }
        *(uchar4*)(mp + ((((size_t)b << 10) + q) << 8) + (c << 4) + (quad << 2)) = out;
    } else {
        const int idx = (blockIdx.x - 3136) * 256 + tid;   // 1M items
        const int token = idx >> 7, k2 = (idx & 127) * 2;  // token = b*1024 + n
        const int b = token >> 10, n = token & 1023;
        const float e = (float)k2 * (1.0f / 256.0f);
        const float freq = exp2f(-13.287712379549449f * e);
        const float ang = (float)n * freq;
        const float2 nd = *(const float2*)(nodes + ((size_t)(n * 8 + b)) * 256 + k2);
        __bf16* p = xinb + (size_t)token * 256 + k2;
        p[0] = (__bf16)(nd.x + sinf(ang));
        p[1] = (__bf16)(nd.y + cosf(ang));
    }
}

// ---------------------------------------------------------------------------
// gemmW: D^T = W * X^T, full-strip register preload.
// Wave owns 32 output channels (2 m-tiles). ALL weight A-frags for the strip
// are loaded upfront (16 x 16B in flight per lane; K=512 in two halves),
// then a pure MFMA + ds_read loop. ZERO barriers, ZERO mid-loop loads (K<=256).
// ---------------------------------------------------------------------------
template<int KK, int NJ>
__device__ __forceinline__ void gemmW(const __bf16* __restrict__ wrow,
                                      const __bf16* __restrict__ x0,
                                      const __bf16* __restrict__ x1,
                                      f32x4 acc[2][2])
{
    constexpr int NKC = KK / 32;
    bf16x8 wA[2][8];
    #pragma unroll
    for (int kc = 0; kc < (NKC > 8 ? 8 : NKC); ++kc)
        #pragma unroll
        for (int t = 0; t < 2; ++t)
            wA[t][kc] = *(const bf16x8*)(wrow + (size_t)(t * 16) * KK + kc * 32);
    #pragma unroll
    for (int t = 0; t < 2; ++t) {
        acc[t][0] = (f32x4){0.f, 0.f, 0.f, 0.f};
        if (NJ == 2) acc[t][1] = (f32x4){0.f, 0.f, 0.f, 0.f};
    }
    if constexpr (NKC <= 8) {
        #pragma unroll
        for (int kc = 0; kc < NKC; ++kc) {
            const bf16x8 b0 = *(const bf16x8*)(x0 + kc * 32);
            bf16x8 b1;
            if (NJ == 2) b1 = *(const bf16x8*)(x1 + kc * 32);
            #pragma unroll
            for (int t = 0; t < 2; ++t) {
                acc[t][0] = __builtin_amdgcn_mfma_f32_16x16x32_bf16(wA[t][kc], b0, acc[t][0], 0, 0, 0);
                if (NJ == 2)
                    acc[t][1] = __builtin_amdgcn_mfma_f32_16x16x32_bf16(wA[t][kc], b1, acc[t][1], 0, 0, 0);
            }
        }
    } else {
        #pragma unroll
        for (int kc = 0; kc < 8; ++kc) {
            const bf16x8 b0 = *(const bf16x8*)(x0 + kc * 32);
            bf16x8 b1;
            if (NJ == 2) b1 = *(const bf16x8*)(x1 + kc * 32);
            #pragma unroll
            for (int t = 0; t < 2; ++t) {
                acc[t][0] = __builtin_amdgcn_mfma_f32_16x16x32_bf16(wA[t][kc], b0, acc[t][0], 0, 0, 0);
                if (NJ == 2)
                    acc[t][1] = __builtin_amdgcn_mfma_f32_16x16x32_bf16(wA[t][kc], b1, acc[t][1], 0, 0, 0);
            }
            #pragma unroll
            for (int t = 0; t < 2; ++t)   // refill with chunk kc+8 (needed 8 chunks later)
                wA[t][kc] = *(const bf16x8*)(wrow + (size_t)(t * 16) * KK + (kc + 8) * 32);
        }
        #pragma unroll
        for (int kc = 8; kc < 16; ++kc) {
            const bf16x8 b0 = *(const bf16x8*)(x0 + kc * 32);
            bf16x8 b1;
            if (NJ == 2) b1 = *(const bf16x8*)(x1 + kc * 32);
            #pragma unroll
            for (int t = 0; t < 2; ++t) {
                acc[t][0] = __builtin_amdgcn_mfma_f32_16x16x32_bf16(wA[t][kc - 8], b0, acc[t][0], 0, 0, 0);
                if (NJ == 2)
                    acc[t][1] = __builtin_amdgcn_mfma_f32_16x16x32_bf16(wA[t][kc - 8], b1, acc[t][1], 0, 0, 0);
            }
        }
    }
}

// ---------------------------------------------------------------------------
// layer_k: fused transformer block slab, D^T form, 512 thr = 8 waves =
// 8 m-strips of 32 channels; NJ*16 tokens per block.
//   stage A: y = Ain @ w0 + b0 (+xres) -> LN(g1,be1) -> trans
//   FFN: h1 = relu(. @ w1 + b1) -> trans; y2 = h1 @ w2 + b2 + LN1 -> LN2
//   QKV: q(scaled)/k -> (B,H,N,DH) b64; v -> V^T scatter (head h = wave id)
//   BNOUT (grid=1, NJ=1): batch-norm over b at n=0 -> d_out
// ---------------------------------------------------------------------------
template<bool RESID, bool FFN, bool QKV, bool N0ROWS, bool XGATE, bool BNOUT, int NJ>
__global__ __launch_bounds__(512)
void layer_k(const __bf16* __restrict__ Ain, const float* __restrict__ xres,
             const __bf16* __restrict__ w0, const float* __restrict__ b0,
             const float* __restrict__ g1, const float* __restrict__ be1,
             const __bf16* __restrict__ w1, const float* __restrict__ b1_,
             const __bf16* __restrict__ w2, const float* __restrict__ b2_,
             const float* __restrict__ g2, const float* __restrict__ be2,
             const __bf16* __restrict__ wq, const float* __restrict__ bq, int qfull,
             const float* __restrict__ bng, const float* __restrict__ bnb,
             float* __restrict__ xout,
             __bf16* __restrict__ qb, __bf16* __restrict__ kb, __bf16* __restrict__ vtb)
{
    __shared__ __bf16 trans[32][TSTR];
    __shared__ float red[8][32][2];

    const int tid = threadIdx.x;
    const int lane = tid & 63;
    const int wv = tid >> 6;                 // 0..7 = m-strip / head
    const int col = lane & 15, quad = lane >> 4;
    const int row0 = blockIdx.x * (NJ * 16);
    const int ms = wv * 32;

    // ---- stage Ain -> trans ----
    #pragma unroll
    for (int i = 0; i < NJ; ++i) {
        const int v = i * 512 + tid;
        const int rw = v >> 5, cc = (v & 31) * 8;
        const int rg = N0ROWS ? ((rw & 7) << 10) : (row0 + rw);
        *(bf16x8*)&trans[rw][cc] = *(const bf16x8*)(Ain + (size_t)rg * 256 + cc);
    }
    __syncthreads();

    const __bf16* x0 = &trans[col][quad * 8];
    const __bf16* x1 = &trans[16 + col][quad * 8];
    int tg[2];
    #pragma unroll
    for (int j = 0; j < NJ; ++j)
        tg[j] = N0ROWS ? ((j * 16 + col) & 7) << 10 : (row0 + j * 16 + col);

    // ---- stage A ----
    f32x4 acc[2][2];
    gemmW<256, NJ>(w0 + (size_t)(ms + col) * 256 + quad * 8, x0, x1, acc);

    float val[2][2][4];   // [j][t][r]
    {
        float4 bb4[2], gm4[2], bt4[2];
        #pragma unroll
        for (int t = 0; t < 2; ++t) {
            const int cb = ms + t * 16 + quad * 4;
            bb4[t] = *(const float4*)&b0[cb];
            gm4[t] = *(const float4*)&g1[cb];
            bt4[t] = *(const float4*)&be1[cb];
        }
        #pragma unroll
        for (int j = 0; j < NJ; ++j) {
            float s1 = 0.f, s2 = 0.f;
            #pragma unroll
            for (int t = 0; t < 2; ++t) {
                float4 xr4 = {0.f, 0.f, 0.f, 0.f};
                if (RESID) xr4 = *(const float4*)&xres[(size_t)tg[j] * 256 + ms + t * 16 + quad * 4];
                const float* bbp = (const float*)&bb4[t];
                const float* xrp = (const float*)&xr4;
                #pragma unroll
                for (int r = 0; r < 4; ++r) {
                    float v = acc[t][j][r] + bbp[r] + xrp[r];
                    val[j][t][r] = v; s1 += v; s2 += v * v;
                }
            }
            s1 += __shfl_xor(s1, 16); s1 += __shfl_xor(s1, 32);
            s2 += __shfl_xor(s2, 16); s2 += __shfl_xor(s2, 32);
            if (quad == 0) { red[wv][j * 16 + col][0] = s1; red[wv][j * 16 + col][1] = s2; }
        }
        __syncthreads();
        #pragma unroll
        for (int j = 0; j < NJ; ++j) {
            const int tk = j * 16 + col;
            float s1 = 0.f, s2 = 0.f;
            #pragma unroll
            for (int w = 0; w < 8; ++w) { s1 += red[w][tk][0]; s2 += red[w][tk][1]; }
            const float mu = s1 * (1.0f / 256.0f);
            const float rv = rsqrtf(s2 * (1.0f / 256.0f) - mu * mu + 1e-5f);
            #pragma unroll
            for (int t = 0; t < 2; ++t) {
                const float* gmp = (const float*)&gm4[t];
                const float* btp = (const float*)&bt4[t];
                bf16x4 o4; float4 of;
                #pragma unroll
                for (int r = 0; r < 4; ++r) {
                    const float o = (val[j][t][r] - mu) * rv * gmp[r] + btp[r];
                    val[j][t][r] = o;
                    o4[r] = (__bf16)o;
                    ((float*)&of)[r] = o;
                }
                *(bf16x4*)&trans[tk][ms + t * 16 + quad * 4] = o4;
                if (!FFN)
                    *(float4*)&xout[(size_t)tg[j] * 256 + ms + t * 16 + quad * 4] = of;
            }
        }
        __syncthreads();
    }

    if (FFN) {
        // ---- h1 = relu(LN1 @ W1 + b1), M=512 in two m-passes ----
        bf16x4 h1p[2][2][2];   // [mh][j][t]
        #pragma unroll
        for (int mh = 0; mh < 2; ++mh) {
            f32x4 a1[2][2];
            gemmW<256, NJ>(w1 + (size_t)(mh * 256 + ms + col) * 256 + quad * 8, x0, x1, a1);
            #pragma unroll
            for (int t = 0; t < 2; ++t) {
                const float4 bh4 = *(const float4*)&b1_[mh * 256 + ms + t * 16 + quad * 4];
                const float* bhp = (const float*)&bh4;
                #pragma unroll
                for (int j = 0; j < NJ; ++j)
                    #pragma unroll
                    for (int r = 0; r < 4; ++r)
                        h1p[mh][j][t][r] = (__bf16)fmaxf(a1[t][j][r] + bhp[r], 0.f);
            }
        }
        __syncthreads();
        #pragma unroll
        for (int mh = 0; mh < 2; ++mh)
            #pragma unroll
            for (int j = 0; j < NJ; ++j)
                #pragma unroll
                for (int t = 0; t < 2; ++t)
                    *(bf16x4*)&trans[j * 16 + col][mh * 256 + ms + t * 16 + quad * 4] = h1p[mh][j][t];
        __syncthreads();

        // ---- y2 = h1 @ W2 + b2 + LN1 -> LN2 ----
        f32x4 a2[2][2];
        gemmW<512, NJ>(w2 + (size_t)(ms + col) * 512 + quad * 8, x0, x1, a2);

        float4 bb4[2], gm4[2], bt4[2];
        #pragma unroll
        for (int t = 0; t < 2; ++t) {
            const int cb = ms + t * 16 + quad * 4;
            bb4[t] = *(const float4*)&b2_[cb];
            gm4[t] = *(const float4*)&g2[cb];
            bt4[t] = *(const float4*)&be2[cb];
        }
        #pragma unroll
        for (int j = 0; j < NJ; ++j) {
            float s1 = 0.f, s2 = 0.f;
            #pragma unroll
            for (int t = 0; t < 2; ++t) {
                const float* bbp = (const float*)&bb4[t];
                #pragma unroll
                for (int r = 0; r < 4; ++r) {
                    const float v = a2[t][j][r] + bbp[r] + val[j][t][r];
                    val[j][t][r] = v; s1 += v; s2 += v * v;
                }
            }
            s1 += __shfl_xor(s1, 16); s1 += __shfl_xor(s1, 32);
            s2 += __shfl_xor(s2, 16); s2 += __shfl_xor(s2, 32);
            if (quad == 0) { red[wv][j * 16 + col][0] = s1; red[wv][j * 16 + col][1] = s2; }
        }
        __syncthreads();
        #pragma unroll
        for (int j = 0; j < NJ; ++j) {
            const int tk = j * 16 + col;
            float s1 = 0.f, s2 = 0.f;
            #pragma unroll
            for (int w = 0; w < 8; ++w) { s1 += red[w][tk][0]; s2 += red[w][tk][1]; }
            const float mu = s1 * (1.0f / 256.0f);
            const float rv = rsqrtf(s2 * (1.0f / 256.0f) - mu * mu + 1e-5f);
            #pragma unroll
            for (int t = 0; t < 2; ++t) {
                const float* gmp = (const float*)&gm4[t];
                const float* btp = (const float*)&bt4[t];
                bf16x4 o4; float4 of;
                #pragma unroll
                for (int r = 0; r < 4; ++r) {
                    const float o = (val[j][t][r] - mu) * rv * gmp[r] + btp[r];
                    val[j][t][r] = o;
                    o4[r] = (__bf16)o;
                    ((float*)&of)[r] = o;
                }
                if (QKV) *(bf16x4*)&trans[tk][ms + t * 16 + quad * 4] = o4;
                if (!BNOUT) {
                    const bool wr = XGATE ? ((tg[j] & 1023) == 0) : true;
                    if (wr) *(float4*)&xout[(size_t)tg[j] * 256 + ms + t * 16 + quad * 4] = of;
                }
            }
        }
        if (BNOUT) {
            #pragma unroll
            for (int t = 0; t < 2; ++t) {
                const int cb = ms + t * 16 + quad * 4;
                const float4 g4 = *(const float4*)&bng[cb];
                const float4 bB = *(const float4*)&bnb[cb];
                float4 of;
                #pragma unroll
                for (int r = 0; r < 4; ++r) {
                    float s1 = val[0][t][r], s2 = val[0][t][r] * val[0][t][r];
                    s1 += __shfl_xor(s1, 1); s2 += __shfl_xor(s2, 1);
                    s1 += __shfl_xor(s1, 2); s2 += __shfl_xor(s2, 2);
                    s1 += __shfl_xor(s1, 4); s2 += __shfl_xor(s2, 4);
                    s1 += __shfl_xor(s1, 8); s2 += __shfl_xor(s2, 8);
                    const float mu = s1 * (1.0f / 16.0f);     // 2x duplicated 8-sum
                    const float rv = rsqrtf(s2 * (1.0f / 16.0f) - mu * mu + 1e-5f);
                    ((float*)&of)[r] = (val[0][t][r] - mu) * rv * ((const float*)&g4)[r]
                                       + ((const float*)&bB)[r];
                }
                if (col < 8)
                    *(float4*)&xout[(size_t)col * 256 + cb] = of;
            }
        }
        __syncthreads();
    }

    if (QKV) {
        const int b_ = N0ROWS ? 0 : (row0 >> 10);
        const bool qneed = qfull || ((row0 & 1023) < 128);
        const int h = wv;                    // strip == head
        for (int cg = 0; cg < 3; ++cg) {
            if (cg == 0 && !qneed) continue;
            f32x4 aq[2][2];
            gemmW<256, NJ>(wq + (size_t)(cg * 256 + ms + col) * 256 + quad * 8, x0, x1, aq);
            const float qs = (cg == 0) ? 0.25505402616305625f : 1.0f;  // log2e/sqrt(32)
            #pragma unroll
            for (int t = 0; t < 2; ++t) {
                const int dhb = t * 16 + quad * 4;
                const float4 bq4 = *(const float4*)&bq[cg * 256 + ms + dhb];
                const float* bqp = (const float*)&bq4;
                #pragma unroll
                for (int j = 0; j < NJ; ++j) {
                    const int n = tg[j] & 1023;
                    if (cg == 2) {
                        #pragma unroll
                        for (int r = 0; r < 4; ++r)
                            vtb[((size_t)(b_ * 8 + h) * 32 + dhb + r) * 1024 + n] =
                                (__bf16)(aq[t][j][r] + bqp[r]);
                    } else {
                        bf16x4 p;
                        #pragma unroll
                        for (int r = 0; r < 4; ++r)
                            p[r] = (__bf16)((aq[t][j][r] + bqp[r]) * qs);
                        __bf16* dst = (cg == 0) ? qb : kb;
                        *(bf16x4*)&dst[((size_t)(b_ * 8 + h) * 1024 + n) * 32 + dhb] = p;
                    }
                }
            }
        }
    }
}

// ---------------------------------------------------------------------------
// MFMA flash attention (unchanged). Grid (64 bh-swizzled, q-chunks).
// ---------------------------------------------------------------------------
__global__ __launch_bounds__(256)
void attn_mfma(const __bf16* __restrict__ Qb, const __bf16* __restrict__ Kb,
               const __bf16* __restrict__ Vt, const unsigned char* __restrict__ MP,
               __bf16* __restrict__ O)
{
    __shared__ __bf16 pbuf[2][4][2][16][72];
    const int tid = threadIdx.x;
    const int lane = tid & 63;
    const int wv = tid >> 6;
    const int col = lane & 15;
    const int quad = lane >> 4;
    const int xr = blockIdx.x;
    const int bh = ((xr & 7) << 3) | (xr >> 3);     // XCD = x%8 = batch b
    const int b = bh >> 3, h = bh & 7;
    const int qbase = blockIdx.y * 128 + wv * 32;
    const int hsel = (h < 2) ? 0 : 1;
    const bool masked = (h < 6);

    bf16x8 qf[2];
    #pragma unroll
    for (int j = 0; j < 2; ++j)
        qf[j] = *(const bf16x8*)(Qb + ((size_t)bh * Nn + qbase + j * 16 + col) * DHc + quad * 8);

    bf16x8 onesf;
    {
        const __bf16 one = (__bf16)1.0f, zero = (__bf16)0.0f;
        #pragma unroll
        for (int j = 0; j < 8; ++j) onesf[j] = (col == 0) ? one : zero;
    }

    f32x4 O0[2], O1[2], OL[2];
    #pragma unroll
    for (int j = 0; j < 2; ++j) {
        O0[j] = (f32x4){0.f, 0.f, 0.f, 0.f};
        O1[j] = (f32x4){0.f, 0.f, 0.f, 0.f};
        OL[j] = (f32x4){0.f, 0.f, 0.f, 0.f};
    }
    const f32x4 zf = {0.f, 0.f, 0.f, 0.f};
    const __bf16* kbase = Kb + (size_t)bh * Nn * DHc;

    bf16x8 kf[4];
    #pragma unroll
    for (int t = 0; t < 4; ++t)
        kf[t] = *(const bf16x8*)(kbase + (size_t)(t * 16 + col) * DHc + quad * 8);

    for (int c = 0; c < 16; ++c) {
        bf16x8 kn[4];
        if (c < 15)
            #pragma unroll
            for (int t = 0; t < 4; ++t)
                kn[t] = *(const bf16x8*)(kbase + (size_t)((c + 1) * 64 + t * 16 + col) * DHc + quad * 8);
        uchar4 mk[2];
        if (masked)
            #pragma unroll
            for (int j = 0; j < 2; ++j)
                mk[j] = *(const uchar4*)(MP + ((((size_t)b << 10) + qbase + j * 16 + col) << 8)
                                            + (c << 4) + (quad << 2));
        #pragma unroll
        for (int j = 0; j < 2; ++j) {
            f32x4 S[4];
            #pragma unroll
            for (int t = 0; t < 4; ++t)
                S[t] = __builtin_amdgcn_mfma_f32_16x16x32_bf16(kf[t], qf[j], zf, 0, 0, 0);
            if (masked) {
                const unsigned char mb2[4] = {mk[j].x, mk[j].y, mk[j].z, mk[j].w};
                #pragma unroll
                for (int t = 0; t < 4; ++t)
                    #pragma unroll
                    for (int r = 0; r < 4; ++r)
                        if (!((mb2[t] >> (2 * r + hsel)) & 1)) S[t][r] = -INFINITY;
            }
            #pragma unroll
            for (int t = 0; t < 4; ++t) {
                bf16x4 p4;
                #pragma unroll
                for (int r = 0; r < 4; ++r)
                    p4[r] = (__bf16)__builtin_amdgcn_exp2f(S[t][r]);
                *(bf16x4*)(&pbuf[c & 1][wv][j][col][t * 16 + quad * 4]) = p4;
            }
        }
        const __bf16* vp = Vt + (size_t)bh * DHc * Nn + c * 64 + quad * 8;
        #pragma unroll
        for (int kh = 0; kh < 2; ++kh) {
            const bf16x8 v0 = *(const bf16x8*)(vp + (size_t)col * Nn + kh * 32);
            const bf16x8 v1 = *(const bf16x8*)(vp + (size_t)(col + 16) * Nn + kh * 32);
            #pragma unroll
            for (int j = 0; j < 2; ++j) {
                const bf16x8 pf = *(const bf16x8*)(&pbuf[c & 1][wv][j][col][kh * 32 + quad * 8]);
                O0[j] = __builtin_amdgcn_mfma_f32_16x16x32_bf16(pf, v0, O0[j], 0, 0, 0);
                O1[j] = __builtin_amdgcn_mfma_f32_16x16x32_bf16(pf, v1, O1[j], 0, 0, 0);
                OL[j] = __builtin_amdgcn_mfma_f32_16x16x32_bf16(pf, onesf, OL[j], 0, 0, 0);
            }
        }
        if (c < 15)
            #pragma unroll
            for (int t = 0; t < 4; ++t) kf[t] = kn[t];
    }
    #pragma unroll
    for (int j = 0; j < 2; ++j)
        #pragma unroll
        for (int r = 0; r < 4; ++r) {
            const float Lr = __shfl(OL[j][r], lane & 48);
            const float inv = 1.0f / Lr;
            const int q = qbase + j * 16 + quad * 4 + r;
            __bf16* op = O + ((size_t)(b * 1024 + q)) * 256 + h * 32 + col;
            op[0]  = (__bf16)(O0[j][r] * inv);
            op[16] = (__bf16)(O1[j][r] * inv);
        }
}

extern "C" void kernel_launch(void* const* d_in, const int* in_sizes, int n_in,
                              void* d_out, int out_size, void* d_ws, size_t ws_size,
                              hipStream_t stream)
{
    const float* nodes   = (const float*)d_in[0];
    const int*   dist    = (const int*)  d_in[1];
    const float* W_in    = (const float*)d_in[2];
    const float* b_in    = (const float*)d_in[3];
    const float* ln_in_g = (const float*)d_in[4];
    const float* ln_in_b = (const float*)d_in[5];
    const float* Wqkv    = (const float*)d_in[6];
    const float* bqkv    = (const float*)d_in[7];
    const float* Wo      = (const float*)d_in[8];
    const float* bo      = (const float*)d_in[9];
    const float* ln1_g   = (const float*)d_in[10];
    const float* ln1_b   = (const float*)d_in[11];
    const float* W1      = (const float*)d_in[12];
    const float* b1      = (const float*)d_in[13];
    const float* W2      = (const float*)d_in[14];
    const float* b2      = (const float*)d_in[15];
    const float* ln2_g   = (const float*)d_in[16];
    const float* ln2_b   = (const float*)d_in[17];
    const float* bn_g    = (const float*)d_in[18];
    const float* bn_b    = (const float*)d_in[19];

    // workspace (byte offsets), 28.25 MB used
    char* ws = (char*)d_ws;
    float*  x   = (float*)(ws);                          // 8 MB fp32 residual (B,N,HID)
    unsigned char* mp = (unsigned char*)(ws + 8388608);  // 2 MB packed mask
    __bf16* wt  = (__bf16*)(ws + 10485760);              // 2.25 MB weights^T
    __bf16* qb  = (__bf16*)(ws + 12845056);              // 4 MB
    __bf16* kb  = (__bf16*)(ws + 17039360);              // 4 MB
    __bf16* vtb = (__bf16*)(ws + 21233664);              // 4 MB (V^T)
    __bf16* ob  = (__bf16*)(ws + 25427968);              // 4 MB attn out
    __bf16* xinb = ob;   // aliases ob (ob first written after fused1 consumed xinb)

    WCvtArgs wa;
    wa.src[0] = W_in;           wa.K[0] = 256; wa.M[0] = 256; wa.dstOff[0] = 0;
    wa.src[1] = Wqkv;           wa.K[1] = 256; wa.M[1] = 768; wa.dstOff[1] = 65536;
    wa.src[2] = Wqkv + 196608;  wa.K[2] = 256; wa.M[2] = 768; wa.dstOff[2] = 262144;
    wa.src[3] = Wo;             wa.K[3] = 256; wa.M[3] = 256; wa.dstOff[3] = 458752;
    wa.src[4] = Wo + 65536;     wa.K[4] = 256; wa.M[4] = 256; wa.dstOff[4] = 524288;
    wa.src[5] = W1;             wa.K[5] = 256; wa.M[5] = 512; wa.dstOff[5] = 589824;
    wa.src[6] = W1 + 131072;    wa.K[6] = 256; wa.M[6] = 512; wa.dstOff[6] = 720896;
    wa.src[7] = W2;             wa.K[7] = 512; wa.M[7] = 256; wa.dstOff[7] = 851968;
    wa.src[8] = W2 + 131072;    wa.K[8] = 512; wa.M[8] = 256; wa.dstOff[8] = 983040;
    for (int i = 0; i < 9; ++i) wa.tiles[i] = (wa.K[i] >> 5) * (wa.M[i] >> 5);

    prep_k<<<7232, 256, 0, stream>>>(wa, wt, dist, mp, nodes, xinb);

    // fused1: x = LN(xin @ W_in + b_in); QKV layer 0 (full q)
    layer_k<false, false, true, false, false, false, 2><<<256, 512, 0, stream>>>(
        xinb, nullptr, wt, b_in, ln_in_g, ln_in_b,
        nullptr, nullptr, nullptr, nullptr, nullptr, nullptr,
        wt + 65536, bqkv, 1, nullptr, nullptr, x, qb, kb, vtb);

    attn_mfma<<<dim3(64, 8), 256, 0, stream>>>(qb, kb, vtb, mp, ob);

    // fused2: Wo0+LN1+FFN0+LN2 (x stored only n==0); QKV layer 1 (q only n<128)
    layer_k<true, true, true, false, true, false, 2><<<256, 512, 0, stream>>>(
        ob, x, wt + 458752, bo, ln1_g, ln1_b,
        wt + 589824, b1, wt + 851968, b2, ln2_g, ln2_b,
        wt + 262144, bqkv + 768, 0, nullptr, nullptr, x, qb, kb, vtb);

    // attn layer 1: only q in [0,128) needed (output consumed only at n==0)
    attn_mfma<<<dim3(64, 1), 256, 0, stream>>>(qb, kb, vtb, mp, ob);

    // fused3: Wo1+LN1+FFN1+LN2 + batch-norm on the 8 n==0 rows (1 block)
    layer_k<true, true, false, true, true, true, 1><<<1, 512, 0, stream>>>(
        ob, x, wt + 524288, bo + 256, ln1_g + 256, ln1_b + 256,
        wt + 720896, b1 + 512, wt + 983040, b2 + 256, ln2_g + 256, ln2_b + 256,
        nullptr, nullptr, 0, bn_g, bn_b, (float*)d_out, nullptr, nullptr, nullptr);
}

// Round 12
// 258.624 us; speedup vs baseline: 1.0336x; 1.0004x over previous
//
#include <hip/hip_runtime.h>
#include <math.h>

// dims
constexpr int Nn = 1024, Bb = 8, HIDc = 256, Hh = 8, DHc = 32;
constexpr int TSTR = 520;   // trans row stride (bf16 elems)

typedef __bf16 bf16x8 __attribute__((ext_vector_type(8)));
typedef __bf16 bf16x4 __attribute__((ext_vector_type(4)));
typedef float  f32x4  __attribute__((ext_vector_type(4)));

// ---------------------------------------------------------------------------
// prep_k: fused one-time preprocessing (unchanged).
// ---------------------------------------------------------------------------
struct WCvtArgs {
    const float* src[9];
    int K[9], M[9], dstOff[9], tiles[9];
};

__global__ __launch_bounds__(256)
void prep_k(WCvtArgs a, __bf16* __restrict__ Wt,
            const int* __restrict__ dist, unsigned char* __restrict__ mp,
            const float* __restrict__ nodes, __bf16* __restrict__ xinb)
{
    __shared__ float ts[32][33];
    const int tid = threadIdx.x;
    if (blockIdx.x < 1088) {
        int bid = blockIdx.x, i = 0;
        while (bid >= a.tiles[i]) { bid -= a.tiles[i]; ++i; }
        const int K = a.K[i], M = a.M[i];
        const int tilesM = M >> 5;
        const int m0 = (bid % tilesM) << 5, k0 = (bid / tilesM) << 5;
        const float* src = a.src[i];
        __bf16* dst = Wt + a.dstOff[i];
        const int tx = tid & 31, ty = tid >> 5;
        #pragma unroll
        for (int j = 0; j < 4; ++j)
            ts[ty + 8 * j][tx] = src[(size_t)(k0 + ty + 8 * j) * M + m0 + tx];
        __syncthreads();
        #pragma unroll
        for (int j = 0; j < 4; ++j)
            dst[(size_t)(m0 + ty + 8 * j) * K + k0 + tx] = (__bf16)ts[tx][ty + 8 * j];
    } else if (blockIdx.x < 3136) {
        const int idx = (blockIdx.x - 1088) * 256 + tid;   // 524288 items
        const int quad = idx & 3, c = (idx >> 2) & 15, q = (idx >> 6) & 1023, b = idx >> 16;
        const int* dp = dist + ((((size_t)b << 10) + q) << 10) + c * 64 + quad * 4;
        uchar4 out;
        unsigned char* po = &out.x;
        #pragma unroll
        for (int t = 0; t < 4; ++t) {
            const int4 v = *(const int4*)(dp + t * 16);
            unsigned int code = 0;
            const int dd[4] = {v.x, v.y, v.z, v.w};
            #pragma unroll
            for (int r = 0; r < 4; ++r)
                code |= ((dd[r] == 1 ? 1u : 0u) | (dd[r] >= 1 ? 2u : 0u)) << (2 * r);
            po[t] = (unsigned char)code;
        }
        *(uchar4*)(mp + ((((size_t)b << 10) + q) << 8) + (c << 4) + (quad << 2)) = out;
    } else {
        const int idx = (blockIdx.x - 3136) * 256 + tid;   // 1M items
        const int token = idx >> 7, k2 = (idx & 127) * 2;  // token = b*1024 + n
        const int b = token >> 10, n = token & 1023;
        const float e = (float)k2 * (1.0f / 256.0f);
        const float freq = exp2f(-13.287712379549449f * e);
        const float ang = (float)n * freq;
        const float2 nd = *(const float2*)(nodes + ((size_t)(n * 8 + b)) * 256 + k2);
        __bf16* p = xinb + (size_t)token * 256 + k2;
        p[0] = (__bf16)(nd.x + sinf(ang));
        p[1] = (__bf16)(nd.y + cosf(ang));
    }
}

// ---------------------------------------------------------------------------
// gemmW: D^T = W * X^T, FULL-strip register preload (needs 256 VGPR budget —
// layer_k is __launch_bounds__(512,2)). All NKC*2 weight frags loaded
// back-to-back (all in flight), then pure MFMA + ds_read loop. Zero barriers.
// ---------------------------------------------------------------------------
template<int KK, int NJ>
__device__ __forceinline__ void gemmW(const __bf16* __restrict__ wrow,
                                      const __bf16* __restrict__ x0,
                                      const __bf16* __restrict__ x1,
                                      f32x4 acc[2][2])
{
    constexpr int NKC = KK / 32;
    bf16x8 wA[2][NKC];
    #pragma unroll
    for (int kc = 0; kc < NKC; ++kc)
        #pragma unroll
        for (int t = 0; t < 2; ++t)
            wA[t][kc] = *(const bf16x8*)(wrow + (size_t)(t * 16) * KK + kc * 32);
    #pragma unroll
    for (int t = 0; t < 2; ++t) {
        acc[t][0] = (f32x4){0.f, 0.f, 0.f, 0.f};
        if (NJ == 2) acc[t][1] = (f32x4){0.f, 0.f, 0.f, 0.f};
    }
    #pragma unroll
    for (int kc = 0; kc < NKC; ++kc) {
        const bf16x8 b0 = *(const bf16x8*)(x0 + kc * 32);
        bf16x8 b1;
        if (NJ == 2) b1 = *(const bf16x8*)(x1 + kc * 32);
        #pragma unroll
        for (int t = 0; t < 2; ++t) {
            acc[t][0] = __builtin_amdgcn_mfma_f32_16x16x32_bf16(wA[t][kc], b0, acc[t][0], 0, 0, 0);
            if (NJ == 2)
                acc[t][1] = __builtin_amdgcn_mfma_f32_16x16x32_bf16(wA[t][kc], b1, acc[t][1], 0, 0, 0);
        }
    }
}

// ---------------------------------------------------------------------------
// layer_k: fused transformer block slab, D^T form, 512 thr = 8 waves =
// 8 m-strips of 32 channels; NJ*16 tokens per block.
// __launch_bounds__(512, 2): 2 waves/EU = 8 waves/CU = our 1 resident block,
// unlocking ~256 VGPR/lane so the full weight strip stays in flight.
// ---------------------------------------------------------------------------
template<bool RESID, bool FFN, bool QKV, bool N0ROWS, bool XGATE, bool BNOUT, int NJ>
__global__ __launch_bounds__(512, 2)
void layer_k(const __bf16* __restrict__ Ain, const float* __restrict__ xres,
             const __bf16* __restrict__ w0, const float* __restrict__ b0,
             const float* __restrict__ g1, const float* __restrict__ be1,
             const __bf16* __restrict__ w1, const float* __restrict__ b1_,
             const __bf16* __restrict__ w2, const float* __restrict__ b2_,
             const float* __restrict__ g2, const float* __restrict__ be2,
             const __bf16* __restrict__ wq, const float* __restrict__ bq, int qfull,
             const float* __restrict__ bng, const float* __restrict__ bnb,
             float* __restrict__ xout,
             __bf16* __restrict__ qb, __bf16* __restrict__ kb, __bf16* __restrict__ vtb)
{
    __shared__ __bf16 trans[32][TSTR];
    __shared__ float red[8][32][2];

    const int tid = threadIdx.x;
    const int lane = tid & 63;
    const int wv = tid >> 6;                 // 0..7 = m-strip / head
    const int col = lane & 15, quad = lane >> 4;
    const int row0 = blockIdx.x * (NJ * 16);
    const int ms = wv * 32;

    // ---- stage Ain -> trans ----
    #pragma unroll
    for (int i = 0; i < NJ; ++i) {
        const int v = i * 512 + tid;
        const int rw = v >> 5, cc = (v & 31) * 8;
        const int rg = N0ROWS ? ((rw & 7) << 10) : (row0 + rw);
        *(bf16x8*)&trans[rw][cc] = *(const bf16x8*)(Ain + (size_t)rg * 256 + cc);
    }
    __syncthreads();

    const __bf16* x0 = &trans[col][quad * 8];
    const __bf16* x1 = &trans[16 + col][quad * 8];
    int tg[2];
    #pragma unroll
    for (int j = 0; j < NJ; ++j)
        tg[j] = N0ROWS ? ((j * 16 + col) & 7) << 10 : (row0 + j * 16 + col);

    // ---- stage A ----
    f32x4 acc[2][2];
    gemmW<256, NJ>(w0 + (size_t)(ms + col) * 256 + quad * 8, x0, x1, acc);

    float val[2][2][4];   // [j][t][r]
    {
        float4 bb4[2], gm4[2], bt4[2];
        #pragma unroll
        for (int t = 0; t < 2; ++t) {
            const int cb = ms + t * 16 + quad * 4;
            bb4[t] = *(const float4*)&b0[cb];
            gm4[t] = *(const float4*)&g1[cb];
            bt4[t] = *(const float4*)&be1[cb];
        }
        #pragma unroll
        for (int j = 0; j < NJ; ++j) {
            float s1 = 0.f, s2 = 0.f;
            #pragma unroll
            for (int t = 0; t < 2; ++t) {
                float4 xr4 = {0.f, 0.f, 0.f, 0.f};
                if (RESID) xr4 = *(const float4*)&xres[(size_t)tg[j] * 256 + ms + t * 16 + quad * 4];
                const float* bbp = (const float*)&bb4[t];
                const float* xrp = (const float*)&xr4;
                #pragma unroll
                for (int r = 0; r < 4; ++r) {
                    float v = acc[t][j][r] + bbp[r] + xrp[r];
                    val[j][t][r] = v; s1 += v; s2 += v * v;
                }
            }
            s1 += __shfl_xor(s1, 16); s1 += __shfl_xor(s1, 32);
            s2 += __shfl_xor(s2, 16); s2 += __shfl_xor(s2, 32);
            if (quad == 0) { red[wv][j * 16 + col][0] = s1; red[wv][j * 16 + col][1] = s2; }
        }
        __syncthreads();
        #pragma unroll
        for (int j = 0; j < NJ; ++j) {
            const int tk = j * 16 + col;
            float s1 = 0.f, s2 = 0.f;
            #pragma unroll
            for (int w = 0; w < 8; ++w) { s1 += red[w][tk][0]; s2 += red[w][tk][1]; }
            const float mu = s1 * (1.0f / 256.0f);
            const float rv = rsqrtf(s2 * (1.0f / 256.0f) - mu * mu + 1e-5f);
            #pragma unroll
            for (int t = 0; t < 2; ++t) {
                const float* gmp = (const float*)&gm4[t];
                const float* btp = (const float*)&bt4[t];
                bf16x4 o4; float4 of;
                #pragma unroll
                for (int r = 0; r < 4; ++r) {
                    const float o = (val[j][t][r] - mu) * rv * gmp[r] + btp[r];
                    val[j][t][r] = o;
                    o4[r] = (__bf16)o;
                    ((float*)&of)[r] = o;
                }
                *(bf16x4*)&trans[tk][ms + t * 16 + quad * 4] = o4;
                if (!FFN)
                    *(float4*)&xout[(size_t)tg[j] * 256 + ms + t * 16 + quad * 4] = of;
            }
        }
        __syncthreads();
    }

    if (FFN) {
        // ---- h1 = relu(LN1 @ W1 + b1), M=512 in two m-passes ----
        bf16x4 h1p[2][2][2];   // [mh][j][t]
        #pragma unroll
        for (int mh = 0; mh < 2; ++mh) {
            f32x4 a1[2][2];
            gemmW<256, NJ>(w1 + (size_t)(mh * 256 + ms + col) * 256 + quad * 8, x0, x1, a1);
            #pragma unroll
            for (int t = 0; t < 2; ++t) {
                const float4 bh4 = *(const float4*)&b1_[mh * 256 + ms + t * 16 + quad * 4];
                const float* bhp = (const float*)&bh4;
                #pragma unroll
                for (int j = 0; j < NJ; ++j)
                    #pragma unroll
                    for (int r = 0; r < 4; ++r)
                        h1p[mh][j][t][r] = (__bf16)fmaxf(a1[t][j][r] + bhp[r], 0.f);
            }
        }
        __syncthreads();
        #pragma unroll
        for (int mh = 0; mh < 2; ++mh)
            #pragma unroll
            for (int j = 0; j < NJ; ++j)
                #pragma unroll
                for (int t = 0; t < 2; ++t)
                    *(bf16x4*)&trans[j * 16 + col][mh * 256 + ms + t * 16 + quad * 4] = h1p[mh][j][t];
        __syncthreads();

        // ---- y2 = h1 @ W2 + b2 + LN1 -> LN2 ----
        f32x4 a2[2][2];
        gemmW<512, NJ>(w2 + (size_t)(ms + col) * 512 + quad * 8, x0, x1, a2);

        float4 bb4[2], gm4[2], bt4[2];
        #pragma unroll
        for (int t = 0; t < 2; ++t) {
            const int cb = ms + t * 16 + quad * 4;
            bb4[t] = *(const float4*)&b2_[cb];
            gm4[t] = *(const float4*)&g2[cb];
            bt4[t] = *(const float4*)&be2[cb];
        }
        #pragma unroll
        for (int j = 0; j < NJ; ++j) {
            float s1 = 0.f, s2 = 0.f;
            #pragma unroll
            for (int t = 0; t < 2; ++t) {
                const float* bbp = (const float*)&bb4[t];
                #pragma unroll
                for (int r = 0; r < 4; ++r) {
                    const float v = a2[t][j][r] + bbp[r] + val[j][t][r];
                    val[j][t][r] = v; s1 += v; s2 += v * v;
                }
            }
            s1 += __shfl_xor(s1, 16); s1 += __shfl_xor(s1, 32);
            s2 += __shfl_xor(s2, 16); s2 += __shfl_xor(s2, 32);
            if (quad == 0) { red[wv][j * 16 + col][0] = s1; red[wv][j * 16 + col][1] = s2; }
        }
        __syncthreads();
        #pragma unroll
        for (int j = 0; j < NJ; ++j) {
            const int tk = j * 16 + col;
            float s1 = 0.f, s2 = 0.f;
            #pragma unroll
            for (int w = 0; w < 8; ++w) { s1 += red[w][tk][0]; s2 += red[w][tk][1]; }
            const float mu = s1 * (1.0f / 256.0f);
            const float rv = rsqrtf(s2 * (1.0f / 256.0f) - mu * mu + 1e-5f);
            #pragma unroll
            for (int t = 0; t < 2; ++t) {
                const float* gmp = (const float*)&gm4[t];
                const float* btp = (const float*)&bt4[t];
                bf16x4 o4; float4 of;
                #pragma unroll
                for (int r = 0; r < 4; ++r) {
                    const float o = (val[j][t][r] - mu) * rv * gmp[r] + btp[r];
                    val[j][t][r] = o;
                    o4[r] = (__bf16)o;
                    ((float*)&of)[r] = o;
                }
                if (QKV) *(bf16x4*)&trans[tk][ms + t * 16 + quad * 4] = o4;
                if (!BNOUT) {
                    const bool wr = XGATE ? ((tg[j] & 1023) == 0) : true;
                    if (wr) *(float4*)&xout[(size_t)tg[j] * 256 + ms + t * 16 + quad * 4] = of;
                }
            }
        }
        if (BNOUT) {
            #pragma unroll
            for (int t = 0; t < 2; ++t) {
                const int cb = ms + t * 16 + quad * 4;
                const float4 g4 = *(const float4*)&bng[cb];
                const float4 bB = *(const float4*)&bnb[cb];
                float4 of;
                #pragma unroll
                for (int r = 0; r < 4; ++r) {
                    float s1 = val[0][t][r], s2 = val[0][t][r] * val[0][t][r];
                    s1 += __shfl_xor(s1, 1); s2 += __shfl_xor(s2, 1);
                    s1 += __shfl_xor(s1, 2); s2 += __shfl_xor(s2, 2);
                    s1 += __shfl_xor(s1, 4); s2 += __shfl_xor(s2, 4);
                    s1 += __shfl_xor(s1, 8); s2 += __shfl_xor(s2, 8);
                    const float mu = s1 * (1.0f / 16.0f);     // 2x duplicated 8-sum
                    const float rv = rsqrtf(s2 * (1.0f / 16.0f) - mu * mu + 1e-5f);
                    ((float*)&of)[r] = (val[0][t][r] - mu) * rv * ((const float*)&g4)[r]
                                       + ((const float*)&bB)[r];
                }
                if (col < 8)
                    *(float4*)&xout[(size_t)col * 256 + cb] = of;
            }
        }
        __syncthreads();
    }

    if (QKV) {
        const int b_ = N0ROWS ? 0 : (row0 >> 10);
        const bool qneed = qfull || ((row0 & 1023) < 128);
        const int h = wv;                    // strip == head
        for (int cg = 0; cg < 3; ++cg) {
            if (cg == 0 && !qneed) continue;
            f32x4 aq[2][2];
            gemmW<256, NJ>(wq + (size_t)(cg * 256 + ms + col) * 256 + quad * 8, x0, x1, aq);
            const float qs = (cg == 0) ? 0.25505402616305625f : 1.0f;  // log2e/sqrt(32)
            #pragma unroll
            for (int t = 0; t < 2; ++t) {
                const int dhb = t * 16 + quad * 4;
                const float4 bq4 = *(const float4*)&bq[cg * 256 + ms + dhb];
                const float* bqp = (const float*)&bq4;
                #pragma unroll
                for (int j = 0; j < NJ; ++j) {
                    const int n = tg[j] & 1023;
                    if (cg == 2) {
                        #pragma unroll
                        for (int r = 0; r < 4; ++r)
                            vtb[((size_t)(b_ * 8 + h) * 32 + dhb + r) * 1024 + n] =
                                (__bf16)(aq[t][j][r] + bqp[r]);
                    } else {
                        bf16x4 p;
                        #pragma unroll
                        for (int r = 0; r < 4; ++r)
                            p[r] = (__bf16)((aq[t][j][r] + bqp[r]) * qs);
                        __bf16* dst = (cg == 0) ? qb : kb;
                        *(bf16x4*)&dst[((size_t)(b_ * 8 + h) * 1024 + n) * 32 + dhb] = p;
                    }
                }
            }
        }
    }
}

// ---------------------------------------------------------------------------
// MFMA flash attention (unchanged). Grid (64 bh-swizzled, q-chunks).
// ---------------------------------------------------------------------------
__global__ __launch_bounds__(256)
void attn_mfma(const __bf16* __restrict__ Qb, const __bf16* __restrict__ Kb,
               const __bf16* __restrict__ Vt, const unsigned char* __restrict__ MP,
               __bf16* __restrict__ O)
{
    __shared__ __bf16 pbuf[2][4][2][16][72];
    const int tid = threadIdx.x;
    const int lane = tid & 63;
    const int wv = tid >> 6;
    const int col = lane & 15;
    const int quad = lane >> 4;
    const int xr = blockIdx.x;
    const int bh = ((xr & 7) << 3) | (xr >> 3);     // XCD = x%8 = batch b
    const int b = bh >> 3, h = bh & 7;
    const int qbase = blockIdx.y * 128 + wv * 32;
    const int hsel = (h < 2) ? 0 : 1;
    const bool masked = (h < 6);

    bf16x8 qf[2];
    #pragma unroll
    for (int j = 0; j < 2; ++j)
        qf[j] = *(const bf16x8*)(Qb + ((size_t)bh * Nn + qbase + j * 16 + col) * DHc + quad * 8);

    bf16x8 onesf;
    {
        const __bf16 one = (__bf16)1.0f, zero = (__bf16)0.0f;
        #pragma unroll
        for (int j = 0; j < 8; ++j) onesf[j] = (col == 0) ? one : zero;
    }

    f32x4 O0[2], O1[2], OL[2];
    #pragma unroll
    for (int j = 0; j < 2; ++j) {
        O0[j] = (f32x4){0.f, 0.f, 0.f, 0.f};
        O1[j] = (f32x4){0.f, 0.f, 0.f, 0.f};
        OL[j] = (f32x4){0.f, 0.f, 0.f, 0.f};
    }
    const f32x4 zf = {0.f, 0.f, 0.f, 0.f};
    const __bf16* kbase = Kb + (size_t)bh * Nn * DHc;

    bf16x8 kf[4];
    #pragma unroll
    for (int t = 0; t < 4; ++t)
        kf[t] = *(const bf16x8*)(kbase + (size_t)(t * 16 + col) * DHc + quad * 8);

    for (int c = 0; c < 16; ++c) {
        bf16x8 kn[4];
        if (c < 15)
            #pragma unroll
            for (int t = 0; t < 4; ++t)
                kn[t] = *(const bf16x8*)(kbase + (size_t)((c + 1) * 64 + t * 16 + col) * DHc + quad * 8);
        uchar4 mk[2];
        if (masked)
            #pragma unroll
            for (int j = 0; j < 2; ++j)
                mk[j] = *(const uchar4*)(MP + ((((size_t)b << 10) + qbase + j * 16 + col) << 8)
                                            + (c << 4) + (quad << 2));
        #pragma unroll
        for (int j = 0; j < 2; ++j) {
            f32x4 S[4];
            #pragma unroll
            for (int t = 0; t < 4; ++t)
                S[t] = __builtin_amdgcn_mfma_f32_16x16x32_bf16(kf[t], qf[j], zf, 0, 0, 0);
            if (masked) {
                const unsigned char mb2[4] = {mk[j].x, mk[j].y, mk[j].z, mk[j].w};
                #pragma unroll
                for (int t = 0; t < 4; ++t)
                    #pragma unroll
                    for (int r = 0; r < 4; ++r)
                        if (!((mb2[t] >> (2 * r + hsel)) & 1)) S[t][r] = -INFINITY;
            }
            #pragma unroll
            for (int t = 0; t < 4; ++t) {
                bf16x4 p4;
                #pragma unroll
                for (int r = 0; r < 4; ++r)
                    p4[r] = (__bf16)__builtin_amdgcn_exp2f(S[t][r]);
                *(bf16x4*)(&pbuf[c & 1][wv][j][col][t * 16 + quad * 4]) = p4;
            }
        }
        const __bf16* vp = Vt + (size_t)bh * DHc * Nn + c * 64 + quad * 8;
        #pragma unroll
        for (int kh = 0; kh < 2; ++kh) {
            const bf16x8 v0 = *(const bf16x8*)(vp + (size_t)col * Nn + kh * 32);
            const bf16x8 v1 = *(const bf16x8*)(vp + (size_t)(col + 16) * Nn + kh * 32);
            #pragma unroll
            for (int j = 0; j < 2; ++j) {
                const bf16x8 pf = *(const bf16x8*)(&pbuf[c & 1][wv][j][col][kh * 32 + quad * 8]);
                O0[j] = __builtin_amdgcn_mfma_f32_16x16x32_bf16(pf, v0, O0[j], 0, 0, 0);
                O1[j] = __builtin_amdgcn_mfma_f32_16x16x32_bf16(pf, v1, O1[j], 0, 0, 0);
                OL[j] = __builtin_amdgcn_mfma_f32_16x16x32_bf16(pf, onesf, OL[j], 0, 0, 0);
            }
        }
        if (c < 15)
            #pragma unroll
            for (int t = 0; t < 4; ++t) kf[t] = kn[t];
    }
    #pragma unroll
    for (int j = 0; j < 2; ++j)
        #pragma unroll
        for (int r = 0; r < 4; ++r) {
            const float Lr = __shfl(OL[j][r], lane & 48);
            const float inv = 1.0f / Lr;
            const int q = qbase + j * 16 + quad * 4 + r;
            __bf16* op = O + ((size_t)(b * 1024 + q)) * 256 + h * 32 + col;
            op[0]  = (__bf16)(O0[j][r] * inv);
            op[16] = (__bf16)(O1[j][r] * inv);
        }
}

extern "C" void kernel_launch(void* const* d_in, const int* in_sizes, int n_in,
                              void* d_out, int out_size, void* d_ws, size_t ws_size,
                              hipStream_t stream)
{
    const float* nodes   = (const float*)d_in[0];
    const int*   dist    = (const int*)  d_in[1];
    const float* W_in    = (const float*)d_in[2];
    const float* b_in    = (const float*)d_in[3];
    const float* ln_in_g = (const float*)d_in[4];
    const float* ln_in_b = (const float*)d_in[5];
    const float* Wqkv    = (const float*)d_in[6];
    const float* bqkv    = (const float*)d_in[7];
    const float* Wo      = (const float*)d_in[8];
    const float* bo      = (const float*)d_in[9];
    const float* ln1_g   = (const float*)d_in[10];
    const float* ln1_b   = (const float*)d_in[11];
    const float* W1      = (const float*)d_in[12];
    const float* b1      = (const float*)d_in[13];
    const float* W2      = (const float*)d_in[14];
    const float* b2      = (const float*)d_in[15];
    const float* ln2_g   = (const float*)d_in[16];
    const float* ln2_b   = (const float*)d_in[17];
    const float* bn_g    = (const float*)d_in[18];
    const float* bn_b    = (const float*)d_in[19];

    // workspace (byte offsets), 28.25 MB used
    char* ws = (char*)d_ws;
    float*  x   = (float*)(ws);                          // 8 MB fp32 residual (B,N,HID)
    unsigned char* mp = (unsigned char*)(ws + 8388608);  // 2 MB packed mask
    __bf16* wt  = (__bf16*)(ws + 10485760);              // 2.25 MB weights^T
    __bf16* qb  = (__bf16*)(ws + 12845056);              // 4 MB
    __bf16* kb  = (__bf16*)(ws + 17039360);              // 4 MB
    __bf16* vtb = (__bf16*)(ws + 21233664);              // 4 MB (V^T)
    __bf16* ob  = (__bf16*)(ws + 25427968);              // 4 MB attn out
    __bf16* xinb = ob;   // aliases ob (ob first written after fused1 consumed xinb)

    WCvtArgs wa;
    wa.src[0] = W_in;           wa.K[0] = 256; wa.M[0] = 256; wa.dstOff[0] = 0;
    wa.src[1] = Wqkv;           wa.K[1] = 256; wa.M[1] = 768; wa.dstOff[1] = 65536;
    wa.src[2] = Wqkv + 196608;  wa.K[2] = 256; wa.M[2] = 768; wa.dstOff[2] = 262144;
    wa.src[3] = Wo;             wa.K[3] = 256; wa.M[3] = 256; wa.dstOff[3] = 458752;
    wa.src[4] = Wo + 65536;     wa.K[4] = 256; wa.M[4] = 256; wa.dstOff[4] = 524288;
    wa.src[5] = W1;             wa.K[5] = 256; wa.M[5] = 512; wa.dstOff[5] = 589824;
    wa.src[6] = W1 + 131072;    wa.K[6] = 256; wa.M[6] = 512; wa.dstOff[6] = 720896;
    wa.src[7] = W2;             wa.K[7] = 512; wa.M[7] = 256; wa.dstOff[7] = 851968;
    wa.src[8] = W2 + 131072;    wa.K[8] = 512; wa.M[8] = 256; wa.dstOff[8] = 983040;
    for (int i = 0; i < 9; ++i) wa.tiles[i] = (wa.K[i] >> 5) * (wa.M[i] >> 5);

    prep_k<<<7232, 256, 0, stream>>>(wa, wt, dist, mp, nodes, xinb);

    // fused1: x = LN(xin @ W_in + b_in); QKV layer 0 (full q)
    layer_k<false, false, true, false, false, false, 2><<<256, 512, 0, stream>>>(
        xinb, nullptr, wt, b_in, ln_in_g, ln_in_b,
        nullptr, nullptr, nullptr, nullptr, nullptr, nullptr,
        wt + 65536, bqkv, 1, nullptr, nullptr, x, qb, kb, vtb);

    attn_mfma<<<dim3(64, 8), 256, 0, stream>>>(qb, kb, vtb, mp, ob);

    // fused2: Wo0+LN1+FFN0+LN2 (x stored only n==0); QKV layer 1 (q only n<128)
    layer_k<true, true, true, false, true, false, 2><<<256, 512, 0, stream>>>(
        ob, x, wt + 458752, bo, ln1_g, ln1_b,
        wt + 589824, b1, wt + 851968, b2, ln2_g, ln2_b,
        wt + 262144, bqkv + 768, 0, nullptr, nullptr, x, qb, kb, vtb);

    // attn layer 1: only q in [0,128) needed (output consumed only at n==0)
    attn_mfma<<<dim3(64, 1), 256, 0, stream>>>(qb, kb, vtb, mp, ob);

    // fused3: Wo1+LN1+FFN1+LN2 + batch-norm on the 8 n==0 rows (1 block)
    layer_k<true, true, false, true, true, true, 1><<<1, 512, 0, stream>>>(
        ob, x, wt + 524288, bo + 256, ln1_g + 256, ln1_b + 256,
        wt + 720896, b1 + 512, wt + 983040, b2 + 256, ln2_g + 256, ln2_b + 256,
        nullptr, nullptr, 0, bn_g, bn_b, (float*)d_out, nullptr, nullptr, nullptr);
}

// Round 13
// 238.540 us; speedup vs baseline: 1.1206x; 1.0842x over previous
//
#include <hip/hip_runtime.h>
#include <math.h>

// dims
constexpr int Nn = 1024, Bb = 8, HIDc = 256, Hh = 8, DHc = 32;
constexpr int TSTR = 520;   // trans row stride (bf16 elems)

typedef __bf16 bf16x8 __attribute__((ext_vector_type(8)));
typedef __bf16 bf16x4 __attribute__((ext_vector_type(4)));
typedef float  f32x4  __attribute__((ext_vector_type(4)));

// ---------------------------------------------------------------------------
// prep_k: fused one-time preprocessing (unchanged).
// ---------------------------------------------------------------------------
struct WCvtArgs {
    const float* src[9];
    int K[9], M[9], dstOff[9], tiles[9];
};

__global__ __launch_bounds__(256)
void prep_k(WCvtArgs a, __bf16* __restrict__ Wt,
            const int* __restrict__ dist, unsigned char* __restrict__ mp,
            const float* __restrict__ nodes, __bf16* __restrict__ xinb)
{
    __shared__ float ts[32][33];
    const int tid = threadIdx.x;
    if (blockIdx.x < 1088) {
        int bid = blockIdx.x, i = 0;
        while (bid >= a.tiles[i]) { bid -= a.tiles[i]; ++i; }
        const int K = a.K[i], M = a.M[i];
        const int tilesM = M >> 5;
        const int m0 = (bid % tilesM) << 5, k0 = (bid / tilesM) << 5;
        const float* src = a.src[i];
        __bf16* dst = Wt + a.dstOff[i];
        const int tx = tid & 31, ty = tid >> 5;
        #pragma unroll
        for (int j = 0; j < 4; ++j)
            ts[ty + 8 * j][tx] = src[(size_t)(k0 + ty + 8 * j) * M + m0 + tx];
        __syncthreads();
        #pragma unroll
        for (int j = 0; j < 4; ++j)
            dst[(size_t)(m0 + ty + 8 * j) * K + k0 + tx] = (__bf16)ts[tx][ty + 8 * j];
    } else if (blockIdx.x < 3136) {
        const int idx = (blockIdx.x - 1088) * 256 + tid;   // 524288 items
        const int quad = idx & 3, c = (idx >> 2) & 15, q = (idx >> 6) & 1023, b = idx >> 16;
        const int* dp = dist + ((((size_t)b << 10) + q) << 10) + c * 64 + quad * 4;
        uchar4 out;
        unsigned char* po = &out.x;
        #pragma unroll
        for (int t = 0; t < 4; ++t) {
            const int4 v = *(const int4*)(dp + t * 16);
            unsigned int code = 0;
            const int dd[4] = {v.x, v.y, v.z, v.w};
            #pragma unroll
            for (int r = 0; r < 4; ++r)
                code |= ((dd[r] == 1 ? 1u : 0u) | (dd[r] >= 1 ? 2u : 0u)) << (2 * r);
            po[t] = (unsigned char)code;
        }
        *(uchar4*)(mp + ((((size_t)b << 10) + q) << 8) + (c << 4) + (quad << 2)) = out;
    } else {
        const int idx = (blockIdx.x - 3136) * 256 + tid;   // 1M items
        const int token = idx >> 7, k2 = (idx & 127) * 2;  // token = b*1024 + n
        const int b = token >> 10, n = token & 1023;
        const float e = (float)k2 * (1.0f / 256.0f);
        const float freq = exp2f(-13.287712379549449f * e);
        const float ang = (float)n * freq;
        const float2 nd = *(const float2*)(nodes + ((size_t)(n * 8 + b)) * 256 + k2);
        __bf16* p = xinb + (size_t)token * 256 + k2;
        p[0] = (__bf16)(nd.x + sinf(ang));
        p[1] = (__bf16)(nd.y + cosf(ang));
    }
}

// ---------------------------------------------------------------------------
// gemmW: D^T = W * X^T, full-strip register preload ENFORCED by
// sched_barrier(0): the compiler may not sink the weight loads into the MFMA
// loop (round-12 showed it re-serializes them to save registers otherwise).
// ---------------------------------------------------------------------------
template<int KK, int NJ>
__device__ __forceinline__ void gemmW(const __bf16* __restrict__ wrow,
                                      const __bf16* __restrict__ x0,
                                      const __bf16* __restrict__ x1,
                                      f32x4 acc[2][2])
{
    constexpr int NKC = KK / 32;
    bf16x8 wA[2][NKC];
    #pragma unroll
    for (int kc = 0; kc < NKC; ++kc)
        #pragma unroll
        for (int t = 0; t < 2; ++t)
            wA[t][kc] = *(const bf16x8*)(wrow + (size_t)(t * 16) * KK + kc * 32);
    __builtin_amdgcn_sched_barrier(0);   // all loads stay issued before MFMAs
    #pragma unroll
    for (int t = 0; t < 2; ++t) {
        acc[t][0] = (f32x4){0.f, 0.f, 0.f, 0.f};
        if (NJ == 2) acc[t][1] = (f32x4){0.f, 0.f, 0.f, 0.f};
    }
    #pragma unroll
    for (int kc = 0; kc < NKC; ++kc) {
        const bf16x8 b0 = *(const bf16x8*)(x0 + kc * 32);
        bf16x8 b1;
        if (NJ == 2) b1 = *(const bf16x8*)(x1 + kc * 32);
        #pragma unroll
        for (int t = 0; t < 2; ++t) {
            acc[t][0] = __builtin_amdgcn_mfma_f32_16x16x32_bf16(wA[t][kc], b0, acc[t][0], 0, 0, 0);
            if (NJ == 2)
                acc[t][1] = __builtin_amdgcn_mfma_f32_16x16x32_bf16(wA[t][kc], b1, acc[t][1], 0, 0, 0);
        }
    }
}

// ---------------------------------------------------------------------------
// layer_k: fused transformer block slab (unchanged structure from r12;
// QKV q-pass now gated to blocks containing n==0 when qfull==0).
// ---------------------------------------------------------------------------
template<bool RESID, bool FFN, bool QKV, bool N0ROWS, bool XGATE, bool BNOUT, int NJ>
__global__ __launch_bounds__(512, 2)
void layer_k(const __bf16* __restrict__ Ain, const float* __restrict__ xres,
             const __bf16* __restrict__ w0, const float* __restrict__ b0,
             const float* __restrict__ g1, const float* __restrict__ be1,
             const __bf16* __restrict__ w1, const float* __restrict__ b1_,
             const __bf16* __restrict__ w2, const float* __restrict__ b2_,
             const float* __restrict__ g2, const float* __restrict__ be2,
             const __bf16* __restrict__ wq, const float* __restrict__ bq, int qfull,
             const float* __restrict__ bng, const float* __restrict__ bnb,
             float* __restrict__ xout,
             __bf16* __restrict__ qb, __bf16* __restrict__ kb, __bf16* __restrict__ vtb)
{
    __shared__ __bf16 trans[32][TSTR];
    __shared__ float red[8][32][2];

    const int tid = threadIdx.x;
    const int lane = tid & 63;
    const int wv = tid >> 6;                 // 0..7 = m-strip / head
    const int col = lane & 15, quad = lane >> 4;
    const int row0 = blockIdx.x * (NJ * 16);
    const int ms = wv * 32;

    // ---- stage Ain -> trans ----
    #pragma unroll
    for (int i = 0; i < NJ; ++i) {
        const int v = i * 512 + tid;
        const int rw = v >> 5, cc = (v & 31) * 8;
        const int rg = N0ROWS ? ((rw & 7) << 10) : (row0 + rw);
        *(bf16x8*)&trans[rw][cc] = *(const bf16x8*)(Ain + (size_t)rg * 256 + cc);
    }
    __syncthreads();

    const __bf16* x0 = &trans[col][quad * 8];
    const __bf16* x1 = &trans[16 + col][quad * 8];
    int tg[2];
    #pragma unroll
    for (int j = 0; j < NJ; ++j)
        tg[j] = N0ROWS ? ((j * 16 + col) & 7) << 10 : (row0 + j * 16 + col);

    // ---- stage A ----
    f32x4 acc[2][2];
    gemmW<256, NJ>(w0 + (size_t)(ms + col) * 256 + quad * 8, x0, x1, acc);

    float val[2][2][4];   // [j][t][r]
    {
        float4 bb4[2], gm4[2], bt4[2];
        #pragma unroll
        for (int t = 0; t < 2; ++t) {
            const int cb = ms + t * 16 + quad * 4;
            bb4[t] = *(const float4*)&b0[cb];
            gm4[t] = *(const float4*)&g1[cb];
            bt4[t] = *(const float4*)&be1[cb];
        }
        #pragma unroll
        for (int j = 0; j < NJ; ++j) {
            float s1 = 0.f, s2 = 0.f;
            #pragma unroll
            for (int t = 0; t < 2; ++t) {
                float4 xr4 = {0.f, 0.f, 0.f, 0.f};
                if (RESID) xr4 = *(const float4*)&xres[(size_t)tg[j] * 256 + ms + t * 16 + quad * 4];
                const float* bbp = (const float*)&bb4[t];
                const float* xrp = (const float*)&xr4;
                #pragma unroll
                for (int r = 0; r < 4; ++r) {
                    float v = acc[t][j][r] + bbp[r] + xrp[r];
                    val[j][t][r] = v; s1 += v; s2 += v * v;
                }
            }
            s1 += __shfl_xor(s1, 16); s1 += __shfl_xor(s1, 32);
            s2 += __shfl_xor(s2, 16); s2 += __shfl_xor(s2, 32);
            if (quad == 0) { red[wv][j * 16 + col][0] = s1; red[wv][j * 16 + col][1] = s2; }
        }
        __syncthreads();
        #pragma unroll
        for (int j = 0; j < NJ; ++j) {
            const int tk = j * 16 + col;
            float s1 = 0.f, s2 = 0.f;
            #pragma unroll
            for (int w = 0; w < 8; ++w) { s1 += red[w][tk][0]; s2 += red[w][tk][1]; }
            const float mu = s1 * (1.0f / 256.0f);
            const float rv = rsqrtf(s2 * (1.0f / 256.0f) - mu * mu + 1e-5f);
            #pragma unroll
            for (int t = 0; t < 2; ++t) {
                const float* gmp = (const float*)&gm4[t];
                const float* btp = (const float*)&bt4[t];
                bf16x4 o4; float4 of;
                #pragma unroll
                for (int r = 0; r < 4; ++r) {
                    const float o = (val[j][t][r] - mu) * rv * gmp[r] + btp[r];
                    val[j][t][r] = o;
                    o4[r] = (__bf16)o;
                    ((float*)&of)[r] = o;
                }
                *(bf16x4*)&trans[tk][ms + t * 16 + quad * 4] = o4;
                if (!FFN)
                    *(float4*)&xout[(size_t)tg[j] * 256 + ms + t * 16 + quad * 4] = of;
            }
        }
        __syncthreads();
    }

    if (FFN) {
        // ---- h1 = relu(LN1 @ W1 + b1), M=512 in two m-passes ----
        bf16x4 h1p[2][2][2];   // [mh][j][t]
        #pragma unroll
        for (int mh = 0; mh < 2; ++mh) {
            f32x4 a1[2][2];
            gemmW<256, NJ>(w1 + (size_t)(mh * 256 + ms + col) * 256 + quad * 8, x0, x1, a1);
            #pragma unroll
            for (int t = 0; t < 2; ++t) {
                const float4 bh4 = *(const float4*)&b1_[mh * 256 + ms + t * 16 + quad * 4];
                const float* bhp = (const float*)&bh4;
                #pragma unroll
                for (int j = 0; j < NJ; ++j)
                    #pragma unroll
                    for (int r = 0; r < 4; ++r)
                        h1p[mh][j][t][r] = (__bf16)fmaxf(a1[t][j][r] + bhp[r], 0.f);
            }
        }
        __syncthreads();
        #pragma unroll
        for (int mh = 0; mh < 2; ++mh)
            #pragma unroll
            for (int j = 0; j < NJ; ++j)
                #pragma unroll
                for (int t = 0; t < 2; ++t)
                    *(bf16x4*)&trans[j * 16 + col][mh * 256 + ms + t * 16 + quad * 4] = h1p[mh][j][t];
        __syncthreads();

        // ---- y2 = h1 @ W2 + b2 + LN1 -> LN2 ----
        f32x4 a2[2][2];
        gemmW<512, NJ>(w2 + (size_t)(ms + col) * 512 + quad * 8, x0, x1, a2);

        float4 bb4[2], gm4[2], bt4[2];
        #pragma unroll
        for (int t = 0; t < 2; ++t) {
            const int cb = ms + t * 16 + quad * 4;
            bb4[t] = *(const float4*)&b2_[cb];
            gm4[t] = *(const float4*)&g2[cb];
            bt4[t] = *(const float4*)&be2[cb];
        }
        #pragma unroll
        for (int j = 0; j < NJ; ++j) {
            float s1 = 0.f, s2 = 0.f;
            #pragma unroll
            for (int t = 0; t < 2; ++t) {
                const float* bbp = (const float*)&bb4[t];
                #pragma unroll
                for (int r = 0; r < 4; ++r) {
                    const float v = a2[t][j][r] + bbp[r] + val[j][t][r];
                    val[j][t][r] = v; s1 += v; s2 += v * v;
                }
            }
            s1 += __shfl_xor(s1, 16); s1 += __shfl_xor(s1, 32);
            s2 += __shfl_xor(s2, 16); s2 += __shfl_xor(s2, 32);
            if (quad == 0) { red[wv][j * 16 + col][0] = s1; red[wv][j * 16 + col][1] = s2; }
        }
        __syncthreads();
        #pragma unroll
        for (int j = 0; j < NJ; ++j) {
            const int tk = j * 16 + col;
            float s1 = 0.f, s2 = 0.f;
            #pragma unroll
            for (int w = 0; w < 8; ++w) { s1 += red[w][tk][0]; s2 += red[w][tk][1]; }
            const float mu = s1 * (1.0f / 256.0f);
            const float rv = rsqrtf(s2 * (1.0f / 256.0f) - mu * mu + 1e-5f);
            #pragma unroll
            for (int t = 0; t < 2; ++t) {
                const float* gmp = (const float*)&gm4[t];
                const float* btp = (const float*)&bt4[t];
                bf16x4 o4; float4 of;
                #pragma unroll
                for (int r = 0; r < 4; ++r) {
                    const float o = (val[j][t][r] - mu) * rv * gmp[r] + btp[r];
                    val[j][t][r] = o;
                    o4[r] = (__bf16)o;
                    ((float*)&of)[r] = o;
                }
                if (QKV) *(bf16x4*)&trans[tk][ms + t * 16 + quad * 4] = o4;
                if (!BNOUT) {
                    const bool wr = XGATE ? ((tg[j] & 1023) == 0) : true;
                    if (wr) *(float4*)&xout[(size_t)tg[j] * 256 + ms + t * 16 + quad * 4] = of;
                }
            }
        }
        if (BNOUT) {
            #pragma unroll
            for (int t = 0; t < 2; ++t) {
                const int cb = ms + t * 16 + quad * 4;
                const float4 g4 = *(const float4*)&bng[cb];
                const float4 bB = *(const float4*)&bnb[cb];
                float4 of;
                #pragma unroll
                for (int r = 0; r < 4; ++r) {
                    float s1 = val[0][t][r], s2 = val[0][t][r] * val[0][t][r];
                    s1 += __shfl_xor(s1, 1); s2 += __shfl_xor(s2, 1);
                    s1 += __shfl_xor(s1, 2); s2 += __shfl_xor(s2, 2);
                    s1 += __shfl_xor(s1, 4); s2 += __shfl_xor(s2, 4);
                    s1 += __shfl_xor(s1, 8); s2 += __shfl_xor(s2, 8);
                    const float mu = s1 * (1.0f / 16.0f);     // 2x duplicated 8-sum
                    const float rv = rsqrtf(s2 * (1.0f / 16.0f) - mu * mu + 1e-5f);
                    ((float*)&of)[r] = (val[0][t][r] - mu) * rv * ((const float*)&g4)[r]
                                       + ((const float*)&bB)[r];
                }
                if (col < 8)
                    *(float4*)&xout[(size_t)col * 256 + cb] = of;
            }
        }
        __syncthreads();
    }

    if (QKV) {
        const int b_ = N0ROWS ? 0 : (row0 >> 10);
        const bool qneed = qfull || ((row0 & 1023) == 0);   // only n==0 block needs q
        const int h = wv;                    // strip == head
        for (int cg = 0; cg < 3; ++cg) {
            if (cg == 0 && !qneed) continue;
            f32x4 aq[2][2];
            gemmW<256, NJ>(wq + (size_t)(cg * 256 + ms + col) * 256 + quad * 8, x0, x1, aq);
            const float qs = (cg == 0) ? 0.25505402616305625f : 1.0f;  // log2e/sqrt(32)
            #pragma unroll
            for (int t = 0; t < 2; ++t) {
                const int dhb = t * 16 + quad * 4;
                const float4 bq4 = *(const float4*)&bq[cg * 256 + ms + dhb];
                const float* bqp = (const float*)&bq4;
                #pragma unroll
                for (int j = 0; j < NJ; ++j) {
                    const int n = tg[j] & 1023;
                    if (cg == 2) {
                        #pragma unroll
                        for (int r = 0; r < 4; ++r)
                            vtb[((size_t)(b_ * 8 + h) * 32 + dhb + r) * 1024 + n] =
                                (__bf16)(aq[t][j][r] + bqp[r]);
                    } else {
                        bf16x4 p;
                        #pragma unroll
                        for (int r = 0; r < 4; ++r)
                            p[r] = (__bf16)((aq[t][j][r] + bqp[r]) * qs);
                        __bf16* dst = (cg == 0) ? qb : kb;
                        *(bf16x4*)&dst[((size_t)(b_ * 8 + h) * 1024 + n) * 32 + dhb] = p;
                    }
                }
            }
        }
    }
}

// ---------------------------------------------------------------------------
// MFMA flash attention (layer-0). Grid (64 bh-swizzled, 8 q-chunks).
// K, V, and mask all prefetched one chunk ahead (V/mask were not before).
// ---------------------------------------------------------------------------
__global__ __launch_bounds__(256)
void attn_mfma(const __bf16* __restrict__ Qb, const __bf16* __restrict__ Kb,
               const __bf16* __restrict__ Vt, const unsigned char* __restrict__ MP,
               __bf16* __restrict__ O)
{
    __shared__ __bf16 pbuf[2][4][2][16][72];
    const int tid = threadIdx.x;
    const int lane = tid & 63;
    const int wv = tid >> 6;
    const int col = lane & 15;
    const int quad = lane >> 4;
    const int xr = blockIdx.x;
    const int bh = ((xr & 7) << 3) | (xr >> 3);     // XCD = x%8 = batch b
    const int b = bh >> 3, h = bh & 7;
    const int qbase = blockIdx.y * 128 + wv * 32;
    const int hsel = (h < 2) ? 0 : 1;
    const bool masked = (h < 6);

    bf16x8 qf[2];
    #pragma unroll
    for (int j = 0; j < 2; ++j)
        qf[j] = *(const bf16x8*)(Qb + ((size_t)bh * Nn + qbase + j * 16 + col) * DHc + quad * 8);

    bf16x8 onesf;
    {
        const __bf16 one = (__bf16)1.0f, zero = (__bf16)0.0f;
        #pragma unroll
        for (int j = 0; j < 8; ++j) onesf[j] = (col == 0) ? one : zero;
    }

    f32x4 O0[2], O1[2], OL[2];
    #pragma unroll
    for (int j = 0; j < 2; ++j) {
        O0[j] = (f32x4){0.f, 0.f, 0.f, 0.f};
        O1[j] = (f32x4){0.f, 0.f, 0.f, 0.f};
        OL[j] = (f32x4){0.f, 0.f, 0.f, 0.f};
    }
    const f32x4 zf = {0.f, 0.f, 0.f, 0.f};
    const __bf16* kbase = Kb + (size_t)bh * Nn * DHc;
    const __bf16* vbase = Vt + (size_t)bh * DHc * Nn;
    const unsigned char* mbase = MP + ((size_t)b << 18);

    // preload chunk 0: K rows, V rows, mask
    bf16x8 kf[4], vf[4];
    uchar4 mk[2];
    #pragma unroll
    for (int t = 0; t < 4; ++t)
        kf[t] = *(const bf16x8*)(kbase + (size_t)(t * 16 + col) * DHc + quad * 8);
    #pragma unroll
    for (int kh = 0; kh < 2; ++kh) {
        vf[kh * 2 + 0] = *(const bf16x8*)(vbase + (size_t)col * Nn + kh * 32 + quad * 8);
        vf[kh * 2 + 1] = *(const bf16x8*)(vbase + (size_t)(col + 16) * Nn + kh * 32 + quad * 8);
    }
    if (masked)
        #pragma unroll
        for (int j = 0; j < 2; ++j)
            mk[j] = *(const uchar4*)(mbase + (((size_t)(qbase + j * 16 + col)) << 8) + (quad << 2));

    for (int c = 0; c < 16; ++c) {
        bf16x8 kn[4], vn[4];
        uchar4 mkn[2];
        if (c < 15) {
            #pragma unroll
            for (int t = 0; t < 4; ++t)
                kn[t] = *(const bf16x8*)(kbase + (size_t)((c + 1) * 64 + t * 16 + col) * DHc + quad * 8);
            #pragma unroll
            for (int kh = 0; kh < 2; ++kh) {
                vn[kh * 2 + 0] = *(const bf16x8*)(vbase + (size_t)col * Nn + (c + 1) * 64 + kh * 32 + quad * 8);
                vn[kh * 2 + 1] = *(const bf16x8*)(vbase + (size_t)(col + 16) * Nn + (c + 1) * 64 + kh * 32 + quad * 8);
            }
            if (masked)
                #pragma unroll
                for (int j = 0; j < 2; ++j)
                    mkn[j] = *(const uchar4*)(mbase + (((size_t)(qbase + j * 16 + col)) << 8)
                                                    + ((c + 1) << 4) + (quad << 2));
        }
        #pragma unroll
        for (int j = 0; j < 2; ++j) {
            f32x4 S[4];
            #pragma unroll
            for (int t = 0; t < 4; ++t)
                S[t] = __builtin_amdgcn_mfma_f32_16x16x32_bf16(kf[t], qf[j], zf, 0, 0, 0);
            if (masked) {
                const unsigned char mb2[4] = {mk[j].x, mk[j].y, mk[j].z, mk[j].w};
                #pragma unroll
                for (int t = 0; t < 4; ++t)
                    #pragma unroll
                    for (int r = 0; r < 4; ++r)
                        if (!((mb2[t] >> (2 * r + hsel)) & 1)) S[t][r] = -INFINITY;
            }
            #pragma unroll
            for (int t = 0; t < 4; ++t) {
                bf16x4 p4;
                #pragma unroll
                for (int r = 0; r < 4; ++r)
                    p4[r] = (__bf16)__builtin_amdgcn_exp2f(S[t][r]);
                *(bf16x4*)(&pbuf[c & 1][wv][j][col][t * 16 + quad * 4]) = p4;
            }
        }
        #pragma unroll
        for (int kh = 0; kh < 2; ++kh) {
            #pragma unroll
            for (int j = 0; j < 2; ++j) {
                const bf16x8 pf = *(const bf16x8*)(&pbuf[c & 1][wv][j][col][kh * 32 + quad * 8]);
                O0[j] = __builtin_amdgcn_mfma_f32_16x16x32_bf16(pf, vf[kh * 2 + 0], O0[j], 0, 0, 0);
                O1[j] = __builtin_amdgcn_mfma_f32_16x16x32_bf16(pf, vf[kh * 2 + 1], O1[j], 0, 0, 0);
                OL[j] = __builtin_amdgcn_mfma_f32_16x16x32_bf16(pf, onesf, OL[j], 0, 0, 0);
            }
        }
        if (c < 15) {
            #pragma unroll
            for (int t = 0; t < 4; ++t) { kf[t] = kn[t]; vf[t] = vn[t]; }
            mk[0] = mkn[0]; mk[1] = mkn[1];
        }
    }
    #pragma unroll
    for (int j = 0; j < 2; ++j)
        #pragma unroll
        for (int r = 0; r < 4; ++r) {
            const float Lr = __shfl(OL[j][r], lane & 48);
            const float inv = 1.0f / Lr;
            const int q = qbase + j * 16 + quad * 4 + r;
            __bf16* op = O + ((size_t)(b * 1024 + q)) * 256 + h * 32 + col;
            op[0]  = (__bf16)(O0[j][r] * inv);
            op[16] = (__bf16)(O1[j][r] * inv);
        }
}

// ---------------------------------------------------------------------------
// attn_q0: layer-1 attention for the ONLY consumed query rows (n==0, 8 rows).
// Grid 64 = one block per (b,h); 256 threads x 4 keys = all 1024 keys in one
// parallel sweep (no serial chunk loop). VALU dot + exp2 + shuffle reduce.
// ---------------------------------------------------------------------------
__global__ __launch_bounds__(256)
void attn_q0(const __bf16* __restrict__ Qb, const __bf16* __restrict__ Kb,
             const __bf16* __restrict__ Vt, const unsigned char* __restrict__ MP,
             __bf16* __restrict__ O)
{
    __shared__ float qs[32];
    __shared__ float osum[4][33];
    const int tid = threadIdx.x;
    const int lane = tid & 63, wv = tid >> 6;
    const int bh = blockIdx.x;
    const int b = bh >> 3, h = bh & 7;
    const int hsel = (h < 2) ? 0 : 1;
    const bool masked = (h < 6);

    if (tid < 32) qs[tid] = (float)Qb[(size_t)bh * 1024 * 32 + tid];  // q row n=0
    __syncthreads();
    float qr[32];
    #pragma unroll
    for (int d = 0; d < 32; ++d) qr[d] = qs[d];

    const int k0 = tid * 4;
    const __bf16* kp = Kb + ((size_t)bh * 1024 + k0) * 32;
    unsigned int mbyte = 0xFFu;
    if (masked)
        mbyte = MP[((size_t)b << 18) + ((k0 >> 6) << 4) + (((k0 >> 2) & 3) << 2) + ((k0 >> 4) & 3)];

    float p[4], ps = 0.f;
    #pragma unroll
    for (int r = 0; r < 4; ++r) {
        float s = 0.f;
        #pragma unroll
        for (int c8 = 0; c8 < 4; ++c8) {
            const bf16x8 kv = *(const bf16x8*)(kp + r * 32 + c8 * 8);
            #pragma unroll
            for (int d = 0; d < 8; ++d) s += (float)kv[d] * qr[c8 * 8 + d];
        }
        const bool allow = !masked || ((mbyte >> (2 * r + hsel)) & 1);
        p[r] = allow ? __builtin_amdgcn_exp2f(s) : 0.f;
        ps += p[r];
    }

    float acc[32];
    #pragma unroll
    for (int d = 0; d < 32; ++d) {
        const bf16x4 v4 = *(const bf16x4*)(Vt + ((size_t)bh * 32 + d) * 1024 + k0);
        acc[d] = p[0] * (float)v4[0] + p[1] * (float)v4[1]
               + p[2] * (float)v4[2] + p[3] * (float)v4[3];
    }
    #pragma unroll
    for (int off = 1; off < 64; off <<= 1) {
        ps += __shfl_xor(ps, off);
        #pragma unroll
        for (int d = 0; d < 32; ++d) acc[d] += __shfl_xor(acc[d], off);
    }
    if (lane == 0) {
        #pragma unroll
        for (int d = 0; d < 32; ++d) osum[wv][d] = acc[d];
        osum[wv][32] = ps;
    }
    __syncthreads();
    if (tid < 32) {
        const float o = osum[0][tid] + osum[1][tid] + osum[2][tid] + osum[3][tid];
        const float L = osum[0][32] + osum[1][32] + osum[2][32] + osum[3][32];
        O[((size_t)(b * 1024)) * 256 + h * 32 + tid] = (__bf16)(o / L);
    }
}

extern "C" void kernel_launch(void* const* d_in, const int* in_sizes, int n_in,
                              void* d_out, int out_size, void* d_ws, size_t ws_size,
                              hipStream_t stream)
{
    const float* nodes   = (const float*)d_in[0];
    const int*   dist    = (const int*)  d_in[1];
    const float* W_in    = (const float*)d_in[2];
    const float* b_in    = (const float*)d_in[3];
    const float* ln_in_g = (const float*)d_in[4];
    const float* ln_in_b = (const float*)d_in[5];
    const float* Wqkv    = (const float*)d_in[6];
    const float* bqkv    = (const float*)d_in[7];
    const float* Wo      = (const float*)d_in[8];
    const float* bo      = (const float*)d_in[9];
    const float* ln1_g   = (const float*)d_in[10];
    const float* ln1_b   = (const float*)d_in[11];
    const float* W1      = (const float*)d_in[12];
    const float* b1      = (const float*)d_in[13];
    const float* W2      = (const float*)d_in[14];
    const float* b2      = (const float*)d_in[15];
    const float* ln2_g   = (const float*)d_in[16];
    const float* ln2_b   = (const float*)d_in[17];
    const float* bn_g    = (const float*)d_in[18];
    const float* bn_b    = (const float*)d_in[19];

    // workspace (byte offsets), 28.25 MB used
    char* ws = (char*)d_ws;
    float*  x   = (float*)(ws);                          // 8 MB fp32 residual (B,N,HID)
    unsigned char* mp = (unsigned char*)(ws + 8388608);  // 2 MB packed mask
    __bf16* wt  = (__bf16*)(ws + 10485760);              // 2.25 MB weights^T
    __bf16* qb  = (__bf16*)(ws + 12845056);              // 4 MB
    __bf16* kb  = (__bf16*)(ws + 17039360);              // 4 MB
    __bf16* vtb = (__bf16*)(ws + 21233664);              // 4 MB (V^T)
    __bf16* ob  = (__bf16*)(ws + 25427968);              // 4 MB attn out
    __bf16* xinb = ob;   // aliases ob (ob first written after fused1 consumed xinb)

    WCvtArgs wa;
    wa.src[0] = W_in;           wa.K[0] = 256; wa.M[0] = 256; wa.dstOff[0] = 0;
    wa.src[1] = Wqkv;           wa.K[1] = 256; wa.M[1] = 768; wa.dstOff[1] = 65536;
    wa.src[2] = Wqkv + 196608;  wa.K[2] = 256; wa.M[2] = 768; wa.dstOff[2] = 262144;
    wa.src[3] = Wo;             wa.K[3] = 256; wa.M[3] = 256; wa.dstOff[3] = 458752;
    wa.src[4] = Wo + 65536;     wa.K[4] = 256; wa.M[4] = 256; wa.dstOff[4] = 524288;
    wa.src[5] = W1;             wa.K[5] = 256; wa.M[5] = 512; wa.dstOff[5] = 589824;
    wa.src[6] = W1 + 131072;    wa.K[6] = 256; wa.M[6] = 512; wa.dstOff[6] = 720896;
    wa.src[7] = W2;             wa.K[7] = 512; wa.M[7] = 256; wa.dstOff[7] = 851968;
    wa.src[8] = W2 + 131072;    wa.K[8] = 512; wa.M[8] = 256; wa.dstOff[8] = 983040;
    for (int i = 0; i < 9; ++i) wa.tiles[i] = (wa.K[i] >> 5) * (wa.M[i] >> 5);

    prep_k<<<7232, 256, 0, stream>>>(wa, wt, dist, mp, nodes, xinb);

    // fused1: x = LN(xin @ W_in + b_in); QKV layer 0 (full q)
    layer_k<false, false, true, false, false, false, 2><<<256, 512, 0, stream>>>(
        xinb, nullptr, wt, b_in, ln_in_g, ln_in_b,
        nullptr, nullptr, nullptr, nullptr, nullptr, nullptr,
        wt + 65536, bqkv, 1, nullptr, nullptr, x, qb, kb, vtb);

    attn_mfma<<<dim3(64, 8), 256, 0, stream>>>(qb, kb, vtb, mp, ob);

    // fused2: Wo0+LN1+FFN0+LN2 (x stored only n==0); QKV layer 1 (q only n==0 block)
    layer_k<true, true, true, false, true, false, 2><<<256, 512, 0, stream>>>(
        ob, x, wt + 458752, bo, ln1_g, ln1_b,
        wt + 589824, b1, wt + 851968, b2, ln2_g, ln2_b,
        wt + 262144, bqkv + 768, 0, nullptr, nullptr, x, qb, kb, vtb);

    // attn layer 1: only the 8 n==0 query rows are ever consumed
    attn_q0<<<64, 256, 0, stream>>>(qb, kb, vtb, mp, ob);

    // fused3: Wo1+LN1+FFN1+LN2 + batch-norm on the 8 n==0 rows (1 block)
    layer_k<true, true, false, true, true, true, 1><<<1, 512, 0, stream>>>(
        ob, x, wt + 524288, bo + 256, ln1_g + 256, ln1_b + 256,
        wt + 720896, b1 + 512, wt + 983040, b2 + 256, ln2_g + 256, ln2_b + 256,
        nullptr, nullptr, 0, bn_g, bn_b, (float*)d_out, nullptr, nullptr, nullptr);
}